// Round 4
// baseline (766.327 us; speedup 1.0000x reference)
//
#include <hip/hip_runtime.h>
#include <hip/hip_cooperative_groups.h>

namespace cg = cooperative_groups;

#define NN 100000
#define EE 1600000
#define HH 128
#define GG 64
#define TOT (EE + NN)
#define PSPLIT 8
#define NB 782            // (NN+127)/128 buckets of 128 dst nodes
#define BCAP 4096         // fixed slots per bucket (mean 2046, sigma~45)
#define FCHUNK 4096       // edges per bfill2 block

typedef __attribute__((ext_vector_type(8))) short s16x8;
typedef __attribute__((ext_vector_type(4))) float f32x4;

__device__ __forceinline__ unsigned short f2bf(float f) {
    unsigned u = __float_as_uint(f);
    u = u + 0x7FFFu + ((u >> 16) & 1u);   // round-to-nearest-even
    return (unsigned short)(u >> 16);
}

// ---------------- fused setup: cast + cursor/pool init + bounds(binsearch) + wprep ----------------

__global__ __launch_bounds__(256) void setup_kernel(const float* __restrict__ x,
                                                    const int* __restrict__ batch,
                                                    const float* __restrict__ W0,
                                                    const float* __restrict__ W1,
                                                    const float* __restrict__ W2,
                                                    unsigned* __restrict__ Xbf,
                                                    int* __restrict__ cursor,
                                                    int* __restrict__ gstart, int* __restrict__ gend,
                                                    float* __restrict__ poolsum,
                                                    unsigned short* __restrict__ Wt) {
    int i = blockIdx.x * 256 + threadIdx.x;
    if (i < NN * 64) {                        // cast x -> packed bf16
        float2 v = ((const float2*)x)[i];
        Xbf[i] = (unsigned)f2bf(v.x) | ((unsigned)f2bf(v.y) << 16);
    }
    if (i < NB) cursor[i] = i * BCAP;
    if (i < GG * HH) poolsum[i] = 0.f;
    if (i < GG) {                             // single-writer group bounds via binary search
        int lo = 0, hi = NN;
        while (lo < hi) { int m = (lo + hi) >> 1; if (batch[m] < i) lo = m + 1; else hi = m; }
        int s = lo;
        lo = 0; hi = NN;
        while (lo < hi) { int m = (lo + hi) >> 1; if (batch[m] < i + 1) lo = m + 1; else hi = m; }
        gstart[i] = s;
        gend[i] = lo;
    }
    if (i < 3 * HH * HH) {                    // W fp32 [k][n] -> bf16 [n][k]
        int l = i >> 14, r = i & 16383;
        const float* W = (l == 0) ? W0 : (l == 1) ? W1 : W2;
        int k = r >> 7, n = r & 127;
        Wt[l * HH * HH + n * HH + k] = f2bf(W[r]);
    }
}

// LDS-aggregated bucket scatter into fixed-capacity regions
__global__ __launch_bounds__(256) void bfill2_kernel(const int* __restrict__ ei, int* cursor,
                                                     unsigned* __restrict__ ebuf) {
    __shared__ int h[NB];
    __shared__ int lbase[NB];
    int tid = threadIdx.x;
    size_t e0 = (size_t)blockIdx.x * FCHUNK;
    for (int i = tid; i < NB; i += 256) h[i] = 0;
    __syncthreads();
    unsigned r[16], c[16];
#pragma unroll
    for (int k = 0; k < 16; ++k) {
        size_t e = e0 + (size_t)k * 256 + tid;
        unsigned rr = 0xFFFFFFFFu, cc = 0;
        if (e < EE) {
            rr = (unsigned)ei[e];
            cc = (unsigned)ei[EE + e];
            if (rr >= NN || cc >= NN) rr = 0xFFFFFFFFu;
        }
        r[k] = rr; c[k] = cc;
        if (rr != 0xFFFFFFFFu) atomicAdd(&h[cc >> 7], 1);
    }
    __syncthreads();
    for (int i = tid; i < NB; i += 256) {
        int cnt = h[i];
        lbase[i] = cnt ? atomicAdd(&cursor[i], cnt) : 0;
    }
    __syncthreads();
    for (int i = tid; i < NB; i += 256) h[i] = 0;
    __syncthreads();
#pragma unroll
    for (int k = 0; k < 16; ++k) {
        if (r[k] != 0xFFFFFFFFu) {
            unsigned cc = c[k];
            int b = cc >> 7;
            int slot = lbase[b] + atomicAdd(&h[b], 1);
            if (slot >= b * BCAP && slot < (b + 1) * BCAP)
                ebuf[slot] = (r[k] << 7) | (cc & 127u);
        }
    }
}

// scan over buckets: slot offsets (slots = edges + self-loops); counts from cursor
__global__ void bscan_kernel(const int* __restrict__ cursor, int* __restrict__ bucketSlotStart,
                             int* __restrict__ col_start) {
    __shared__ int ss[1024];
    int t = threadIdx.x;
    int ec = 0, nc = 0;
    if (t < NB) {
        ec = min(max(cursor[t] - t * BCAP, 0), BCAP);
        nc = min(128, NN - t * 128);
    }
    ss[t] = ec + nc;
    __syncthreads();
    for (int off = 1; off < 1024; off <<= 1) {
        int a = 0;
        if (t >= off) a = ss[t - off];
        __syncthreads();
        ss[t] += a;
        __syncthreads();
    }
    if (t < NB) bucketSlotStart[t] = ss[t] - (ec + nc);
    if (t == NB - 1) col_start[NN] = ss[t];
}

// one block per bucket: local count/scan in LDS, emit col_start/dinv/srcv sequentially
__global__ __launch_bounds__(256) void bproc_kernel(const unsigned* __restrict__ ebuf,
                                                    const int* __restrict__ cursor,
                                                    const int* __restrict__ bucketSlotStart,
                                                    int* __restrict__ col_start,
                                                    float* __restrict__ dinv,
                                                    int* __restrict__ srcv) {
    __shared__ unsigned s_e[BCAP];
    __shared__ int s_cnt[128], s_scan[128], s_cur[128];
    int b = blockIdx.x;
    int tid = threadIdx.x;
    int n0 = b * 128;
    int nb = min(128, NN - n0);
    int est = b * BCAP;
    int ecnt = min(max(cursor[b] - est, 0), BCAP);
    if (tid < 128) s_cnt[tid] = 0;
    __syncthreads();
    for (int i = tid; i < ecnt; i += 256) {
        unsigned v = ebuf[est + i];
        s_e[i] = v;
        atomicAdd(&s_cnt[v & 127u], 1);
    }
    __syncthreads();
    int myc = 0;
    if (tid < 128) {
        myc = (tid < nb) ? s_cnt[tid] + 1 : 0;   // +1 self-loop
        s_scan[tid] = myc;
    }
    __syncthreads();
    for (int off = 1; off < 128; off <<= 1) {
        int a = 0;
        if (tid < 128 && tid >= off) a = s_scan[tid - off];
        __syncthreads();
        if (tid < 128) s_scan[tid] += a;
        __syncthreads();
    }
    if (tid < nb) {
        int slotbase = bucketSlotStart[b] + s_scan[tid] - myc;
        col_start[n0 + tid] = slotbase;
        dinv[n0 + tid] = rsqrtf((float)(s_cnt[tid] + 1));
        srcv[slotbase] = n0 + tid;               // self-loop first
        s_cur[tid] = slotbase + 1;
    }
    __syncthreads();
    for (int i = tid; i < ecnt; i += 256) {
        unsigned v = s_e[i];
        int slot = atomicAdd(&s_cur[v & 127u], 1);
        srcv[slot] = (int)(v >> 7);
    }
}

// ---------------- per-layer kernels ----------------

// TWO dst nodes per wave (lanes 0-31 -> node 2w, lanes 32-63 -> node 2w+1).
// rounds padded to a multiple of 6 so every gather sits in a 6-deep pipelined
// batch (R2: -5% vs tail; latency partially hidden by TLP already).
__global__ __launch_bounds__(256) void agg_kernel(const uint4* __restrict__ Xbf4,
                                                  const int* __restrict__ col_start,
                                                  const int* __restrict__ srcv,
                                                  const float* __restrict__ dinv,
                                                  unsigned short* __restrict__ Abf,
                                                  float* __restrict__ gsum,
                                                  float* __restrict__ gsq) {
    if (blockIdx.x == 0 && threadIdx.x < HH) {
        gsum[threadIdx.x] = 0.f;
        gsq[threadIdx.x] = 0.f;
    }
    int wv = (int)((blockIdx.x * blockDim.x + threadIdx.x) >> 6);
    int lane = threadIdx.x & 63;
    int half = lane >> 5;
    int node = 2 * wv + half;
    if (2 * wv >= NN) return;
    bool valid = node < NN;
    int s0 = 0, s1 = 0;
    float dd = 0.f;
    if (valid) { s0 = col_start[node]; s1 = col_start[node + 1]; dd = dinv[node]; }
    int lane31 = lane & 31;
    int qh = (lane >> 4) & 1;     // quarter within half
    int l16 = lane & 15;          // 16 lanes cover one 256B row (uint4 each)
    float acc[8];
#pragma unroll
    for (int j = 0; j < 8; ++j) acc[j] = 0.f;

    for (int base = s0; base < s1; base += 32) {
        int cnt = min(32, s1 - base);
        int msrc = 0;
        float mw = 0.f;
        if (lane31 < cnt) { msrc = srcv[base + lane31]; mw = dinv[msrc] * dd; }
        int rounds = (cnt + 1) >> 1;
        int rp = ((rounds + 5) / 6) * 6;          // pad to full 6-batches
        for (int p = 0; p < rp; p += 6) {
            uint4 u[6];
            float w[6];
#pragma unroll
            for (int k = 0; k < 6; ++k) {
                int idx = (p + k) * 2 + qh;
                int sl = half * 32 + min(idx, 31);
                int src = __shfl(msrc, sl);
                float wk = __shfl(mw, sl);        // 0 beyond cnt (preload zeroed)
                if (idx > 31) wk = 0.f;           // clamped lanes: force dead weight
                w[k] = wk;
                u[k] = Xbf4[(size_t)src * 16 + l16];
            }
#pragma unroll
            for (int k = 0; k < 6; ++k) {
                acc[0] += w[k] * __uint_as_float(u[k].x << 16);
                acc[1] += w[k] * __uint_as_float(u[k].x & 0xFFFF0000u);
                acc[2] += w[k] * __uint_as_float(u[k].y << 16);
                acc[3] += w[k] * __uint_as_float(u[k].y & 0xFFFF0000u);
                acc[4] += w[k] * __uint_as_float(u[k].z << 16);
                acc[5] += w[k] * __uint_as_float(u[k].z & 0xFFFF0000u);
                acc[6] += w[k] * __uint_as_float(u[k].w << 16);
                acc[7] += w[k] * __uint_as_float(u[k].w & 0xFFFF0000u);
            }
        }
    }
#pragma unroll
    for (int j = 0; j < 8; ++j) acc[j] += __shfl_xor(acc[j], 16);   // combine the 2 quarters
    if ((lane & 16) == 0 && valid) {
        uint4 pk;
        pk.x = (unsigned)f2bf(acc[0]) | ((unsigned)f2bf(acc[1]) << 16);
        pk.y = (unsigned)f2bf(acc[2]) | ((unsigned)f2bf(acc[3]) << 16);
        pk.z = (unsigned)f2bf(acc[4]) | ((unsigned)f2bf(acc[5]) << 16);
        pk.w = (unsigned)f2bf(acc[6]) | ((unsigned)f2bf(acc[7]) << 16);
        ((uint4*)Abf)[(size_t)node * 16 + l16] = pk;
    }
}

// Fused GEMM + BN-stats + grid-sync + BN-apply + ReLU, cooperative launch.
// R3 fix: (a) __threadfence release after global atomicAdds, (b) post-sync
// reads of gsum/gsq via agent-scope __hip_atomic_load — plain loads can be
// served stale from per-XCD L2/L1 (guide §Correctness boundaries).
__global__ __launch_bounds__(256, 4) void gemm_fused_kernel(const unsigned short* __restrict__ Abf,
                                                            const unsigned short* __restrict__ Wt,
                                                            const float* __restrict__ bias,
                                                            float* __restrict__ gsum,
                                                            float* __restrict__ gsq,
                                                            const float* __restrict__ g,
                                                            const float* __restrict__ beta,
                                                            unsigned short* __restrict__ Xb16) {
    __shared__ unsigned short wlds[128 * 136];   // row stride 136 bf16 = 272B: no b128 conflicts
    __shared__ float ssum[HH], ssq[HH];
    __shared__ float asc[HH], bsh[HH];
    int tid = threadIdx.x;
    if (tid < HH) { ssum[tid] = 0.f; ssq[tid] = 0.f; }
#pragma unroll
    for (int it = 0; it < 16; ++it) {
        int idx = it * 256 + tid;
        int r = idx >> 5, c = idx & 31;
        *(uint2*)&wlds[r * 136 + c * 4] = *(const uint2*)(Wt + r * HH + c * 4);
    }
    __syncthreads();

    int lane = tid & 63;
    int wave = tid >> 6;
    int mcol = lane & 15;
    int quad = lane >> 4;
    int rowbase = blockIdx.x * 128 + wave * 32;
    int row0 = rowbase + mcol;
    int row1 = row0 + 16;

    f32x4 acc[2][8];
#pragma unroll
    for (int mt = 0; mt < 2; ++mt)
#pragma unroll
        for (int nt = 0; nt < 8; ++nt) acc[mt][nt] = (f32x4){0.f, 0.f, 0.f, 0.f};

    s16x8 zf = {0, 0, 0, 0, 0, 0, 0, 0};
#pragma unroll
    for (int ks = 0; ks < 4; ++ks) {
        int k0 = ks * 32 + quad * 8;
        s16x8 a0 = (row0 < NN) ? *(const s16x8*)(Abf + (size_t)row0 * HH + k0) : zf;
        s16x8 a1 = (row1 < NN) ? *(const s16x8*)(Abf + (size_t)row1 * HH + k0) : zf;
#pragma unroll
        for (int nt = 0; nt < 8; ++nt) {
            s16x8 b = *(const s16x8*)&wlds[(nt * 16 + mcol) * 136 + k0];
            acc[0][nt] = __builtin_amdgcn_mfma_f32_16x16x32_bf16(a0, b, acc[0][nt], 0, 0, 0);
            acc[1][nt] = __builtin_amdgcn_mfma_f32_16x16x32_bf16(a1, b, acc[1][nt], 0, 0, 0);
        }
    }

    // ---- BN column stats from live acc ----
    float s[8], sq[8];
#pragma unroll
    for (int nt = 0; nt < 8; ++nt) { s[nt] = 0.f; sq[nt] = 0.f; }
#pragma unroll
    for (int mt = 0; mt < 2; ++mt) {
        int rbase = rowbase + mt * 16 + quad * 4;
#pragma unroll
        for (int nt = 0; nt < 8; ++nt) {
            float bv = bias[nt * 16 + mcol];
            f32x4 a = acc[mt][nt];
#pragma unroll
            for (int reg = 0; reg < 4; ++reg) {
                if (rbase + reg < NN) {
                    float h = a[reg] + bv;
                    s[nt] += h; sq[nt] += h * h;
                }
            }
        }
    }
#pragma unroll
    for (int nt = 0; nt < 8; ++nt) {
        float v = s[nt];  v += __shfl_xor(v, 16);  v += __shfl_xor(v, 32);
        float w = sq[nt]; w += __shfl_xor(w, 16);  w += __shfl_xor(w, 32);
        if (quad == 0) {
            atomicAdd(&ssum[nt * 16 + mcol], v);
            atomicAdd(&ssq[nt * 16 + mcol], w);
        }
    }
    __syncthreads();
    if (tid < HH) {
        atomicAdd(&gsum[tid], ssum[tid]);     // device-scope
        atomicAdd(&gsq[tid], ssq[tid]);
    }
    __threadfence();                           // release before grid barrier

    // ---- all blocks agree on global stats ----
    cg::this_grid().sync();

    if (tid < HH) {
        float gs = __hip_atomic_load(&gsum[tid], __ATOMIC_RELAXED, __HIP_MEMORY_SCOPE_AGENT);
        float gq = __hip_atomic_load(&gsq[tid], __ATOMIC_RELAXED, __HIP_MEMORY_SCOPE_AGENT);
        float mu = gs * (1.f / (float)NN);
        float var = fmaxf(gq * (1.f / (float)NN) - mu * mu, 0.f);
        float a = g[tid] * rsqrtf(var + 1e-5f);
        asc[tid] = a;
        bsh[tid] = a * (bias[tid] - mu) + beta[tid];   // o = a*acc + bsh (acc pre-bias)
    }
    __syncthreads();

    // ---- apply BN+ReLU to live acc, store bf16 ----
#pragma unroll
    for (int mt = 0; mt < 2; ++mt) {
        int rbase = rowbase + mt * 16 + quad * 4;
#pragma unroll
        for (int nt = 0; nt < 8; ++nt) {
            int col = nt * 16 + mcol;
            float av = asc[col], bv = bsh[col];
            f32x4 a = acc[mt][nt];
#pragma unroll
            for (int reg = 0; reg < 4; ++reg) {
                int r = rbase + reg;
                if (r < NN) {
                    float o = fmaxf(av * a[reg] + bv, 0.f);
                    Xb16[(size_t)r * HH + col] = f2bf(o);
                }
            }
        }
    }
}

// ---- fallback pair (R2-verified): stats then apply as separate launches ----

__global__ __launch_bounds__(256) void gemm_stats_kernel(const unsigned short* __restrict__ Abf,
                                                         const unsigned short* __restrict__ Wt,
                                                         const float* __restrict__ bias,
                                                         float* __restrict__ gsum,
                                                         float* __restrict__ gsq) {
    __shared__ unsigned short wlds[128 * 136];
    __shared__ float ssum[HH], ssq[HH];
    int tid = threadIdx.x;
    if (tid < HH) { ssum[tid] = 0.f; ssq[tid] = 0.f; }
#pragma unroll
    for (int it = 0; it < 16; ++it) {
        int idx = it * 256 + tid;
        int r = idx >> 5, c = idx & 31;
        *(uint2*)&wlds[r * 136 + c * 4] = *(const uint2*)(Wt + r * HH + c * 4);
    }
    __syncthreads();

    int lane = tid & 63;
    int wave = tid >> 6;
    int mcol = lane & 15;
    int quad = lane >> 4;
    int rowbase = blockIdx.x * 128 + wave * 32;
    int row0 = rowbase + mcol;
    int row1 = row0 + 16;

    f32x4 acc[2][8];
#pragma unroll
    for (int mt = 0; mt < 2; ++mt)
#pragma unroll
        for (int nt = 0; nt < 8; ++nt) acc[mt][nt] = (f32x4){0.f, 0.f, 0.f, 0.f};

    s16x8 zf = {0, 0, 0, 0, 0, 0, 0, 0};
#pragma unroll
    for (int ks = 0; ks < 4; ++ks) {
        int k0 = ks * 32 + quad * 8;
        s16x8 a0 = (row0 < NN) ? *(const s16x8*)(Abf + (size_t)row0 * HH + k0) : zf;
        s16x8 a1 = (row1 < NN) ? *(const s16x8*)(Abf + (size_t)row1 * HH + k0) : zf;
#pragma unroll
        for (int nt = 0; nt < 8; ++nt) {
            s16x8 b = *(const s16x8*)&wlds[(nt * 16 + mcol) * 136 + k0];
            acc[0][nt] = __builtin_amdgcn_mfma_f32_16x16x32_bf16(a0, b, acc[0][nt], 0, 0, 0);
            acc[1][nt] = __builtin_amdgcn_mfma_f32_16x16x32_bf16(a1, b, acc[1][nt], 0, 0, 0);
        }
    }

    float s[8], sq[8];
#pragma unroll
    for (int nt = 0; nt < 8; ++nt) { s[nt] = 0.f; sq[nt] = 0.f; }
#pragma unroll
    for (int mt = 0; mt < 2; ++mt) {
        int rbase = rowbase + mt * 16 + quad * 4;
#pragma unroll
        for (int nt = 0; nt < 8; ++nt) {
            float bv = bias[nt * 16 + mcol];
            f32x4 a = acc[mt][nt];
#pragma unroll
            for (int reg = 0; reg < 4; ++reg) {
                if (rbase + reg < NN) {
                    float h = a[reg] + bv;
                    s[nt] += h; sq[nt] += h * h;
                }
            }
        }
    }
#pragma unroll
    for (int nt = 0; nt < 8; ++nt) {
        float v = s[nt];  v += __shfl_xor(v, 16);  v += __shfl_xor(v, 32);
        float w = sq[nt]; w += __shfl_xor(w, 16);  w += __shfl_xor(w, 32);
        if (quad == 0) {
            atomicAdd(&ssum[nt * 16 + mcol], v);
            atomicAdd(&ssq[nt * 16 + mcol], w);
        }
    }
    __syncthreads();
    if (tid < HH) {
        atomicAdd(&gsum[tid], ssum[tid]);
        atomicAdd(&gsq[tid], ssq[tid]);
    }
}

__global__ __launch_bounds__(256) void gemm_apply_kernel(const unsigned short* __restrict__ Abf,
                                                         const unsigned short* __restrict__ Wt,
                                                         const float* __restrict__ bias,
                                                         const float* __restrict__ gsum,
                                                         const float* __restrict__ gsq,
                                                         const float* __restrict__ g,
                                                         const float* __restrict__ beta,
                                                         unsigned short* __restrict__ Xb16) {
    __shared__ unsigned short wlds[128 * 136];
    __shared__ float asc[HH], bsh[HH];
    int tid = threadIdx.x;
#pragma unroll
    for (int it = 0; it < 16; ++it) {
        int idx = it * 256 + tid;
        int r = idx >> 5, c = idx & 31;
        *(uint2*)&wlds[r * 136 + c * 4] = *(const uint2*)(Wt + r * HH + c * 4);
    }
    if (tid < HH) {
        float mu = gsum[tid] * (1.f / (float)NN);
        float var = fmaxf(gsq[tid] * (1.f / (float)NN) - mu * mu, 0.f);
        float a = g[tid] * rsqrtf(var + 1e-5f);
        asc[tid] = a;
        bsh[tid] = a * (bias[tid] - mu) + beta[tid];
    }
    __syncthreads();

    int lane = tid & 63;
    int wave = tid >> 6;
    int mcol = lane & 15;
    int quad = lane >> 4;
    int rowbase = blockIdx.x * 128 + wave * 32;
    int row0 = rowbase + mcol;
    int row1 = row0 + 16;

    f32x4 acc[2][8];
#pragma unroll
    for (int mt = 0; mt < 2; ++mt)
#pragma unroll
        for (int nt = 0; nt < 8; ++nt) acc[mt][nt] = (f32x4){0.f, 0.f, 0.f, 0.f};

    s16x8 zf = {0, 0, 0, 0, 0, 0, 0, 0};
#pragma unroll
    for (int ks = 0; ks < 4; ++ks) {
        int k0 = ks * 32 + quad * 8;
        s16x8 a0 = (row0 < NN) ? *(const s16x8*)(Abf + (size_t)row0 * HH + k0) : zf;
        s16x8 a1 = (row1 < NN) ? *(const s16x8*)(Abf + (size_t)row1 * HH + k0) : zf;
#pragma unroll
        for (int nt = 0; nt < 8; ++nt) {
            s16x8 b = *(const s16x8*)&wlds[(nt * 16 + mcol) * 136 + k0];
            acc[0][nt] = __builtin_amdgcn_mfma_f32_16x16x32_bf16(a0, b, acc[0][nt], 0, 0, 0);
            acc[1][nt] = __builtin_amdgcn_mfma_f32_16x16x32_bf16(a1, b, acc[1][nt], 0, 0, 0);
        }
    }

#pragma unroll
    for (int mt = 0; mt < 2; ++mt) {
        int rbase = rowbase + mt * 16 + quad * 4;
#pragma unroll
        for (int nt = 0; nt < 8; ++nt) {
            int col = nt * 16 + mcol;
            float av = asc[col], bv = bsh[col];
            f32x4 a = acc[mt][nt];
#pragma unroll
            for (int reg = 0; reg < 4; ++reg) {
                int r = rbase + reg;
                if (r < NN) {
                    float o = fmaxf(av * a[reg] + bv, 0.f);
                    Xb16[(size_t)r * HH + col] = f2bf(o);
                }
            }
        }
    }
}

// ---------------- pooling + fc ----------------

__global__ void pool_kernel(const unsigned* __restrict__ Xbf, const int* __restrict__ gstart,
                            const int* __restrict__ gend, float* __restrict__ poolsum) {
    int g = blockIdx.x;
    int sp = blockIdx.y;
    int t = threadIdx.x;           // 64: each handles 2 cols
    int s = gstart[g], e = gend[g];
    if (e <= s) return;
    int len = e - s;
    int chunk = (len + PSPLIT - 1) / PSPLIT;
    int cs = s + sp * chunk;
    int ce = min(cs + chunk, e);
    if (cs >= ce) return;
    float2 acc = make_float2(0.f, 0.f);
    for (int i = cs; i < ce; ++i) {
        unsigned u = Xbf[(size_t)i * 64 + t];
        acc.x += __uint_as_float(u << 16);
        acc.y += __uint_as_float(u & 0xFFFF0000u);
    }
    atomicAdd(&poolsum[g * HH + 2 * t], acc.x);
    atomicAdd(&poolsum[g * HH + 2 * t + 1], acc.y);
}

__global__ void fc_kernel(const float* __restrict__ poolsum, const int* __restrict__ gstart,
                          const int* __restrict__ gend, const float* __restrict__ fc_w,
                          const float* __restrict__ fc_b, float* __restrict__ out) {
    int g = blockIdx.x;
    int o = threadIdx.x;
    int cnt = gend[g] - gstart[g];
    float inv = (cnt > 0) ? (1.f / (float)cnt) : 0.f;
    float acc = fc_b[o];
    for (int k = 0; k < HH; ++k) acc += (poolsum[g * HH + k] * inv) * fc_w[k * HH + o];
    out[g * HH + o] = acc;
}

// ---------------- launch ----------------

extern "C" void kernel_launch(void* const* d_in, const int* in_sizes, int n_in,
                              void* d_out, int out_size, void* d_ws, size_t ws_size,
                              hipStream_t stream) {
    const float* x     = (const float*)d_in[0];
    const int*   ei    = (const int*)d_in[1];
    const int*   batch = (const int*)d_in[2];
    const float* Wl[3]    = {(const float*)d_in[3], (const float*)d_in[7], (const float*)d_in[11]};
    const float* bl[3]    = {(const float*)d_in[4], (const float*)d_in[8], (const float*)d_in[12]};
    const float* gl[3]    = {(const float*)d_in[5], (const float*)d_in[9], (const float*)d_in[13]};
    const float* betal[3] = {(const float*)d_in[6], (const float*)d_in[10], (const float*)d_in[14]};
    const float* fc_w = (const float*)d_in[15];
    const float* fc_b = (const float*)d_in[16];
    float* out = (float*)d_out;

    char* ws = (char*)d_ws;
    size_t off = 0;
    auto take = [&](size_t n) -> void* {
        void* p = ws + off;
        off = (off + n + 255) & ~(size_t)255;
        return p;
    };
    int*   bucketSlotStart = (int*)take((size_t)NB * 4);
    int*   cursor          = (int*)take((size_t)NB * 4);
    unsigned* ebuf         = (unsigned*)take((size_t)NB * BCAP * 4);
    int*   col_start       = (int*)take((size_t)(NN + 1) * 4);
    float* dinv            = (float*)take((size_t)NN * 4);
    int*   srcv            = (int*)take((size_t)TOT * 4);
    float* gsum            = (float*)take(HH * 4);
    float* gsq             = (float*)take(HH * 4);
    int*   gstart          = (int*)take(GG * 4);
    int*   gend            = (int*)take(GG * 4);
    float* poolsum         = (float*)take((size_t)GG * HH * 4);
    unsigned short* wt     = (unsigned short*)take((size_t)3 * HH * HH * 2);
    unsigned* Xbf          = (unsigned*)take((size_t)NN * 64 * 4);
    unsigned short* Abf    = (unsigned short*)take((size_t)NN * HH * 2);

    setup_kernel<<<(NN * 64 + 255) / 256, 256, 0, stream>>>(x, batch, Wl[0], Wl[1], Wl[2],
                                                            Xbf, cursor, gstart, gend, poolsum, wt);
    bfill2_kernel<<<(EE + FCHUNK - 1) / FCHUNK, 256, 0, stream>>>(ei, cursor, ebuf);
    bscan_kernel<<<1, 1024, 0, stream>>>(cursor, bucketSlotStart, col_start);
    bproc_kernel<<<NB, 256, 0, stream>>>(ebuf, cursor, bucketSlotStart, col_start, dinv, srcv);

    const int aggBlocks = (((NN + 1) / 2) * 64 + 255) / 256;   // 2 nodes per wave
    for (int l = 0; l < 3; ++l) {
        const unsigned short* W = wt + (size_t)l * HH * HH;
        const float* bias = bl[l];
        const float* gg = gl[l];
        const float* bb = betal[l];
        unsigned short* xout = (unsigned short*)Xbf;
        agg_kernel<<<aggBlocks, 256, 0, stream>>>((const uint4*)Xbf, col_start, srcv,
                                                  dinv, Abf, gsum, gsq);
        void* args[] = {(void*)&Abf, (void*)&W, (void*)&bias, (void*)&gsum, (void*)&gsq,
                        (void*)&gg, (void*)&bb, (void*)&xout};
        hipError_t cerr = hipLaunchCooperativeKernel((void*)gemm_fused_kernel,
                                                     dim3((NN + 127) / 128), dim3(256),
                                                     args, 0, stream);
        if (cerr != hipSuccess) {
            // fallback: R2-verified split pair (also consumes the pending error state)
            (void)hipGetLastError();
            gemm_stats_kernel<<<(NN + 127) / 128, 256, 0, stream>>>(Abf, W, bias, gsum, gsq);
            gemm_apply_kernel<<<(NN + 127) / 128, 256, 0, stream>>>(Abf, W, bias, gsum, gsq,
                                                                    gg, bb, xout);
        }
    }

    pool_kernel<<<dim3(GG, PSPLIT), 64, 0, stream>>>(Xbf, gstart, gend, poolsum);
    fc_kernel<<<GG, 128, 0, stream>>>(poolsum, gstart, gend, fc_w, fc_b, out);
}

// Round 5
// 576.762 us; speedup vs baseline: 1.3287x; 1.3287x over previous
//
#include <hip/hip_runtime.h>

#define NN 100000
#define EE 1600000
#define HH 128
#define GG 64
#define TOT (EE + NN)
#define PSPLIT 8
#define NB 782            // (NN+127)/128 buckets of 128 dst nodes
#define BCAP 4096         // fixed slots per bucket (mean 2046, sigma~45)
#define FCHUNK 4096       // edges per bfill2 block

typedef __attribute__((ext_vector_type(8))) short s16x8;
typedef __attribute__((ext_vector_type(4))) float f32x4;

__device__ __forceinline__ unsigned short f2bf(float f) {
    unsigned u = __float_as_uint(f);
    u = u + 0x7FFFu + ((u >> 16) & 1u);   // round-to-nearest-even
    return (unsigned short)(u >> 16);
}

// ---------------- fused setup: cast + cursor/pool init + bounds(binsearch) + wprep ----------------

__global__ __launch_bounds__(256) void setup_kernel(const float* __restrict__ x,
                                                    const int* __restrict__ batch,
                                                    const float* __restrict__ W0,
                                                    const float* __restrict__ W1,
                                                    const float* __restrict__ W2,
                                                    unsigned* __restrict__ Xbf,
                                                    int* __restrict__ cursor,
                                                    int* __restrict__ gstart, int* __restrict__ gend,
                                                    float* __restrict__ poolsum,
                                                    unsigned short* __restrict__ Wt) {
    int i = blockIdx.x * 256 + threadIdx.x;
    if (i < NN * 64) {                        // cast x -> packed bf16
        float2 v = ((const float2*)x)[i];
        Xbf[i] = (unsigned)f2bf(v.x) | ((unsigned)f2bf(v.y) << 16);
    }
    if (i < NB) cursor[i] = i * BCAP;
    if (i < GG * HH) poolsum[i] = 0.f;
    if (i < GG) {                             // single-writer group bounds via binary search
        int lo = 0, hi = NN;
        while (lo < hi) { int m = (lo + hi) >> 1; if (batch[m] < i) lo = m + 1; else hi = m; }
        int s = lo;
        lo = 0; hi = NN;
        while (lo < hi) { int m = (lo + hi) >> 1; if (batch[m] < i + 1) lo = m + 1; else hi = m; }
        gstart[i] = s;
        gend[i] = lo;
    }
    if (i < 3 * HH * HH) {                    // W fp32 [k][n] -> bf16 [n][k]
        int l = i >> 14, r = i & 16383;
        const float* W = (l == 0) ? W0 : (l == 1) ? W1 : W2;
        int k = r >> 7, n = r & 127;
        Wt[l * HH * HH + n * HH + k] = f2bf(W[r]);
    }
}

// LDS-aggregated bucket scatter into fixed-capacity regions
__global__ __launch_bounds__(256) void bfill2_kernel(const int* __restrict__ ei, int* cursor,
                                                     unsigned* __restrict__ ebuf) {
    __shared__ int h[NB];
    __shared__ int lbase[NB];
    int tid = threadIdx.x;
    size_t e0 = (size_t)blockIdx.x * FCHUNK;
    for (int i = tid; i < NB; i += 256) h[i] = 0;
    __syncthreads();
    unsigned r[16], c[16];
#pragma unroll
    for (int k = 0; k < 16; ++k) {
        size_t e = e0 + (size_t)k * 256 + tid;
        unsigned rr = 0xFFFFFFFFu, cc = 0;
        if (e < EE) {
            rr = (unsigned)ei[e];
            cc = (unsigned)ei[EE + e];
            if (rr >= NN || cc >= NN) rr = 0xFFFFFFFFu;
        }
        r[k] = rr; c[k] = cc;
        if (rr != 0xFFFFFFFFu) atomicAdd(&h[cc >> 7], 1);
    }
    __syncthreads();
    for (int i = tid; i < NB; i += 256) {
        int cnt = h[i];
        lbase[i] = cnt ? atomicAdd(&cursor[i], cnt) : 0;
    }
    __syncthreads();
    for (int i = tid; i < NB; i += 256) h[i] = 0;
    __syncthreads();
#pragma unroll
    for (int k = 0; k < 16; ++k) {
        if (r[k] != 0xFFFFFFFFu) {
            unsigned cc = c[k];
            int b = cc >> 7;
            int slot = lbase[b] + atomicAdd(&h[b], 1);
            if (slot >= b * BCAP && slot < (b + 1) * BCAP)
                ebuf[slot] = (r[k] << 7) | (cc & 127u);
        }
    }
}

// scan over buckets: slot offsets (slots = edges + self-loops); counts from cursor
__global__ void bscan_kernel(const int* __restrict__ cursor, int* __restrict__ bucketSlotStart,
                             int* __restrict__ col_start) {
    __shared__ int ss[1024];
    int t = threadIdx.x;
    int ec = 0, nc = 0;
    if (t < NB) {
        ec = min(max(cursor[t] - t * BCAP, 0), BCAP);
        nc = min(128, NN - t * 128);
    }
    ss[t] = ec + nc;
    __syncthreads();
    for (int off = 1; off < 1024; off <<= 1) {
        int a = 0;
        if (t >= off) a = ss[t - off];
        __syncthreads();
        ss[t] += a;
        __syncthreads();
    }
    if (t < NB) bucketSlotStart[t] = ss[t] - (ec + nc);
    if (t == NB - 1) col_start[NN] = ss[t];
}

// one block per bucket: local count/scan in LDS, emit col_start/dinv/srcv sequentially
__global__ __launch_bounds__(256) void bproc_kernel(const unsigned* __restrict__ ebuf,
                                                    const int* __restrict__ cursor,
                                                    const int* __restrict__ bucketSlotStart,
                                                    int* __restrict__ col_start,
                                                    float* __restrict__ dinv,
                                                    int* __restrict__ srcv) {
    __shared__ unsigned s_e[BCAP];
    __shared__ int s_cnt[128], s_scan[128], s_cur[128];
    int b = blockIdx.x;
    int tid = threadIdx.x;
    int n0 = b * 128;
    int nb = min(128, NN - n0);
    int est = b * BCAP;
    int ecnt = min(max(cursor[b] - est, 0), BCAP);
    if (tid < 128) s_cnt[tid] = 0;
    __syncthreads();
    for (int i = tid; i < ecnt; i += 256) {
        unsigned v = ebuf[est + i];
        s_e[i] = v;
        atomicAdd(&s_cnt[v & 127u], 1);
    }
    __syncthreads();
    int myc = 0;
    if (tid < 128) {
        myc = (tid < nb) ? s_cnt[tid] + 1 : 0;   // +1 self-loop
        s_scan[tid] = myc;
    }
    __syncthreads();
    for (int off = 1; off < 128; off <<= 1) {
        int a = 0;
        if (tid < 128 && tid >= off) a = s_scan[tid - off];
        __syncthreads();
        if (tid < 128) s_scan[tid] += a;
        __syncthreads();
    }
    if (tid < nb) {
        int slotbase = bucketSlotStart[b] + s_scan[tid] - myc;
        col_start[n0 + tid] = slotbase;
        dinv[n0 + tid] = rsqrtf((float)(s_cnt[tid] + 1));
        srcv[slotbase] = n0 + tid;               // self-loop first
        s_cur[tid] = slotbase + 1;
    }
    __syncthreads();
    for (int i = tid; i < ecnt; i += 256) {
        unsigned v = s_e[i];
        int slot = atomicAdd(&s_cur[v & 127u], 1);
        srcv[slot] = (int)(v >> 7);
    }
}

// ---------------- per-layer kernels ----------------

// TWO dst nodes per wave (lanes 0-31 -> node 2w, lanes 32-63 -> node 2w+1).
// rounds padded to a multiple of 6 so every gather sits in a 6-deep pipelined
// batch (R2: -5% vs tail; latency partially hidden by TLP already).
__global__ __launch_bounds__(256) void agg_kernel(const uint4* __restrict__ Xbf4,
                                                  const int* __restrict__ col_start,
                                                  const int* __restrict__ srcv,
                                                  const float* __restrict__ dinv,
                                                  unsigned short* __restrict__ Abf,
                                                  float* __restrict__ gsum,
                                                  float* __restrict__ gsq) {
    if (blockIdx.x == 0 && threadIdx.x < HH) {
        gsum[threadIdx.x] = 0.f;
        gsq[threadIdx.x] = 0.f;
    }
    int wv = (int)((blockIdx.x * blockDim.x + threadIdx.x) >> 6);
    int lane = threadIdx.x & 63;
    int half = lane >> 5;
    int node = 2 * wv + half;
    if (2 * wv >= NN) return;
    bool valid = node < NN;
    int s0 = 0, s1 = 0;
    float dd = 0.f;
    if (valid) { s0 = col_start[node]; s1 = col_start[node + 1]; dd = dinv[node]; }
    int lane31 = lane & 31;
    int qh = (lane >> 4) & 1;     // quarter within half
    int l16 = lane & 15;          // 16 lanes cover one 256B row (uint4 each)
    float acc[8];
#pragma unroll
    for (int j = 0; j < 8; ++j) acc[j] = 0.f;

    for (int base = s0; base < s1; base += 32) {
        int cnt = min(32, s1 - base);
        int msrc = 0;
        float mw = 0.f;
        if (lane31 < cnt) { msrc = srcv[base + lane31]; mw = dinv[msrc] * dd; }
        int rounds = (cnt + 1) >> 1;
        int rp = ((rounds + 5) / 6) * 6;          // pad to full 6-batches
        for (int p = 0; p < rp; p += 6) {
            uint4 u[6];
            float w[6];
#pragma unroll
            for (int k = 0; k < 6; ++k) {
                int idx = (p + k) * 2 + qh;
                int sl = half * 32 + min(idx, 31);
                int src = __shfl(msrc, sl);
                float wk = __shfl(mw, sl);        // 0 beyond cnt (preload zeroed)
                if (idx > 31) wk = 0.f;           // clamped lanes: force dead weight
                w[k] = wk;
                u[k] = Xbf4[(size_t)src * 16 + l16];
            }
#pragma unroll
            for (int k = 0; k < 6; ++k) {
                acc[0] += w[k] * __uint_as_float(u[k].x << 16);
                acc[1] += w[k] * __uint_as_float(u[k].x & 0xFFFF0000u);
                acc[2] += w[k] * __uint_as_float(u[k].y << 16);
                acc[3] += w[k] * __uint_as_float(u[k].y & 0xFFFF0000u);
                acc[4] += w[k] * __uint_as_float(u[k].z << 16);
                acc[5] += w[k] * __uint_as_float(u[k].z & 0xFFFF0000u);
                acc[6] += w[k] * __uint_as_float(u[k].w << 16);
                acc[7] += w[k] * __uint_as_float(u[k].w & 0xFFFF0000u);
            }
        }
    }
#pragma unroll
    for (int j = 0; j < 8; ++j) acc[j] += __shfl_xor(acc[j], 16);   // combine the 2 quarters
    if ((lane & 16) == 0 && valid) {
        uint4 pk;
        pk.x = (unsigned)f2bf(acc[0]) | ((unsigned)f2bf(acc[1]) << 16);
        pk.y = (unsigned)f2bf(acc[2]) | ((unsigned)f2bf(acc[3]) << 16);
        pk.z = (unsigned)f2bf(acc[4]) | ((unsigned)f2bf(acc[5]) << 16);
        pk.w = (unsigned)f2bf(acc[6]) | ((unsigned)f2bf(acc[7]) << 16);
        ((uint4*)Abf)[(size_t)node * 16 + l16] = pk;
    }
}

// GEMM + BN-stats, stores pre-bias H (bf16) IN PLACE over Abf.
// - W staged in LDS in fragment-major order [nt][ks][quad][mcol][8]: each wave's
//   64 lanes read 64 consecutive 16B chunks -> conflict-free (R4: 400K conflicts
//   from 8-way bank aliasing with the 136-stride row-major layout).
// - In-place H write is safe: each block reads only its own 128 rows as the
//   MFMA A-operand; __syncthreads() after the MFMA loop orders reads vs stores.
__global__ __launch_bounds__(256) void gemm_stats_kernel(unsigned short* __restrict__ Abf,
                                                         const unsigned short* __restrict__ Wt,
                                                         const float* __restrict__ bias,
                                                         float* __restrict__ gsum,
                                                         float* __restrict__ gsq) {
    __shared__ unsigned short wlds[2048 * 8];    // 32 KB, fragment-major
    __shared__ float ssum[HH], ssq[HH];
    int tid = threadIdx.x;
    if (tid < HH) { ssum[tid] = 0.f; ssq[tid] = 0.f; }
    // stage W: chunk c -> n = c&127 (row), k8 = c>>7 (8-col group)
    // dst chunk = (nt*16 + ks*4 + quad)*16 + mcol  where n=(nt,mcol), k8=(ks,quad)
#pragma unroll
    for (int it = 0; it < 8; ++it) {
        int c = it * 256 + tid;
        int n = c & 127, k8 = c >> 7;
        int nt = n >> 4, mcol = n & 15, ks = k8 >> 2, quad = k8 & 3;
        int dst = (nt * 16 + ks * 4 + quad) * 16 + mcol;
        *(uint4*)&wlds[dst * 8] = *(const uint4*)(Wt + n * HH + k8 * 8);
    }
    __syncthreads();

    int lane = tid & 63;
    int wave = tid >> 6;
    int mcol = lane & 15;
    int quad = lane >> 4;
    int rowbase = blockIdx.x * 128 + wave * 32;
    int row0 = rowbase + mcol;
    int row1 = row0 + 16;

    f32x4 acc[2][8];
#pragma unroll
    for (int mt = 0; mt < 2; ++mt)
#pragma unroll
        for (int nt = 0; nt < 8; ++nt) acc[mt][nt] = (f32x4){0.f, 0.f, 0.f, 0.f};

    s16x8 zf = {0, 0, 0, 0, 0, 0, 0, 0};
#pragma unroll
    for (int ks = 0; ks < 4; ++ks) {
        int k0 = ks * 32 + quad * 8;
        s16x8 a0 = (row0 < NN) ? *(const s16x8*)(Abf + (size_t)row0 * HH + k0) : zf;
        s16x8 a1 = (row1 < NN) ? *(const s16x8*)(Abf + (size_t)row1 * HH + k0) : zf;
#pragma unroll
        for (int nt = 0; nt < 8; ++nt) {
            s16x8 b = *(const s16x8*)&wlds[((nt * 16 + ks * 4 + quad) * 16 + mcol) * 8];
            acc[0][nt] = __builtin_amdgcn_mfma_f32_16x16x32_bf16(a0, b, acc[0][nt], 0, 0, 0);
            acc[1][nt] = __builtin_amdgcn_mfma_f32_16x16x32_bf16(a1, b, acc[1][nt], 0, 0, 0);
        }
    }

    __syncthreads();   // all A-loads in this block complete before in-place H stores

    // ---- store pre-bias H (bf16) over Abf + BN column stats from fp32 acc ----
    float s[8], sq[8];
#pragma unroll
    for (int nt = 0; nt < 8; ++nt) { s[nt] = 0.f; sq[nt] = 0.f; }
#pragma unroll
    for (int mt = 0; mt < 2; ++mt) {
        int rbase = rowbase + mt * 16 + quad * 4;
#pragma unroll
        for (int nt = 0; nt < 8; ++nt) {
            int col = nt * 16 + mcol;
            float bv = bias[col];
            f32x4 a = acc[mt][nt];
#pragma unroll
            for (int reg = 0; reg < 4; ++reg) {
                int r = rbase + reg;
                if (r < NN) {
                    float h = a[reg] + bv;
                    s[nt] += h; sq[nt] += h * h;
                    Abf[(size_t)r * HH + col] = f2bf(a[reg]);   // pre-bias H
                }
            }
        }
    }
#pragma unroll
    for (int nt = 0; nt < 8; ++nt) {
        float v = s[nt];  v += __shfl_xor(v, 16);  v += __shfl_xor(v, 32);
        float w = sq[nt]; w += __shfl_xor(w, 16);  w += __shfl_xor(w, 32);
        if (quad == 0) {
            atomicAdd(&ssum[nt * 16 + mcol], v);
            atomicAdd(&ssq[nt * 16 + mcol], w);
        }
    }
    __syncthreads();
    if (tid < HH) {
        atomicAdd(&gsum[tid], ssum[tid]);
        atomicAdd(&gsq[tid], ssq[tid]);
    }
}

// elementwise BN+ReLU: X = relu(a*H + bsh), H read from Abf (bf16, pre-bias).
// Pure streaming pass (51 MB) replacing the 40us MFMA-recompute apply kernel.
__global__ __launch_bounds__(256) void bnrelu_kernel(const uint4* __restrict__ Hb,
                                                     const float* __restrict__ bias,
                                                     const float* __restrict__ gsum,
                                                     const float* __restrict__ gsq,
                                                     const float* __restrict__ g,
                                                     const float* __restrict__ beta,
                                                     uint4* __restrict__ Xbf) {
    __shared__ float asc[HH], bsh[HH];
    int tid = threadIdx.x;
    if (tid < HH) {
        float mu = gsum[tid] * (1.f / (float)NN);
        float var = fmaxf(gsq[tid] * (1.f / (float)NN) - mu * mu, 0.f);
        float a = g[tid] * rsqrtf(var + 1e-5f);
        asc[tid] = a;
        bsh[tid] = a * (bias[tid] - mu) + beta[tid];   // o = a*h + bsh (h pre-bias)
    }
    __syncthreads();
    int stride = gridDim.x * 256;
    for (int e = blockIdx.x * 256 + tid; e < NN * 16; e += stride) {
        uint4 u = Hb[e];
        int c0 = (e & 15) * 8;
        uint4 o;
        float h0, h1, o0, o1;
        h0 = __uint_as_float(u.x << 16);  h1 = __uint_as_float(u.x & 0xFFFF0000u);
        o0 = fmaxf(fmaf(asc[c0 + 0], h0, bsh[c0 + 0]), 0.f);
        o1 = fmaxf(fmaf(asc[c0 + 1], h1, bsh[c0 + 1]), 0.f);
        o.x = (unsigned)f2bf(o0) | ((unsigned)f2bf(o1) << 16);
        h0 = __uint_as_float(u.y << 16);  h1 = __uint_as_float(u.y & 0xFFFF0000u);
        o0 = fmaxf(fmaf(asc[c0 + 2], h0, bsh[c0 + 2]), 0.f);
        o1 = fmaxf(fmaf(asc[c0 + 3], h1, bsh[c0 + 3]), 0.f);
        o.y = (unsigned)f2bf(o0) | ((unsigned)f2bf(o1) << 16);
        h0 = __uint_as_float(u.z << 16);  h1 = __uint_as_float(u.z & 0xFFFF0000u);
        o0 = fmaxf(fmaf(asc[c0 + 4], h0, bsh[c0 + 4]), 0.f);
        o1 = fmaxf(fmaf(asc[c0 + 5], h1, bsh[c0 + 5]), 0.f);
        o.z = (unsigned)f2bf(o0) | ((unsigned)f2bf(o1) << 16);
        h0 = __uint_as_float(u.w << 16);  h1 = __uint_as_float(u.w & 0xFFFF0000u);
        o0 = fmaxf(fmaf(asc[c0 + 6], h0, bsh[c0 + 6]), 0.f);
        o1 = fmaxf(fmaf(asc[c0 + 7], h1, bsh[c0 + 7]), 0.f);
        o.w = (unsigned)f2bf(o0) | ((unsigned)f2bf(o1) << 16);
        Xbf[e] = o;
    }
}

// ---------------- pooling + fc ----------------

__global__ void pool_kernel(const unsigned* __restrict__ Xbf, const int* __restrict__ gstart,
                            const int* __restrict__ gend, float* __restrict__ poolsum) {
    int g = blockIdx.x;
    int sp = blockIdx.y;
    int t = threadIdx.x;           // 64: each handles 2 cols
    int s = gstart[g], e = gend[g];
    if (e <= s) return;
    int len = e - s;
    int chunk = (len + PSPLIT - 1) / PSPLIT;
    int cs = s + sp * chunk;
    int ce = min(cs + chunk, e);
    if (cs >= ce) return;
    float2 acc = make_float2(0.f, 0.f);
    for (int i = cs; i < ce; ++i) {
        unsigned u = Xbf[(size_t)i * 64 + t];
        acc.x += __uint_as_float(u << 16);
        acc.y += __uint_as_float(u & 0xFFFF0000u);
    }
    atomicAdd(&poolsum[g * HH + 2 * t], acc.x);
    atomicAdd(&poolsum[g * HH + 2 * t + 1], acc.y);
}

__global__ void fc_kernel(const float* __restrict__ poolsum, const int* __restrict__ gstart,
                          const int* __restrict__ gend, const float* __restrict__ fc_w,
                          const float* __restrict__ fc_b, float* __restrict__ out) {
    int g = blockIdx.x;
    int o = threadIdx.x;
    int cnt = gend[g] - gstart[g];
    float inv = (cnt > 0) ? (1.f / (float)cnt) : 0.f;
    float acc = fc_b[o];
    for (int k = 0; k < HH; ++k) acc += (poolsum[g * HH + k] * inv) * fc_w[k * HH + o];
    out[g * HH + o] = acc;
}

// ---------------- launch ----------------

extern "C" void kernel_launch(void* const* d_in, const int* in_sizes, int n_in,
                              void* d_out, int out_size, void* d_ws, size_t ws_size,
                              hipStream_t stream) {
    const float* x     = (const float*)d_in[0];
    const int*   ei    = (const int*)d_in[1];
    const int*   batch = (const int*)d_in[2];
    const float* Wl[3]    = {(const float*)d_in[3], (const float*)d_in[7], (const float*)d_in[11]};
    const float* bl[3]    = {(const float*)d_in[4], (const float*)d_in[8], (const float*)d_in[12]};
    const float* gl[3]    = {(const float*)d_in[5], (const float*)d_in[9], (const float*)d_in[13]};
    const float* betal[3] = {(const float*)d_in[6], (const float*)d_in[10], (const float*)d_in[14]};
    const float* fc_w = (const float*)d_in[15];
    const float* fc_b = (const float*)d_in[16];
    float* out = (float*)d_out;

    char* ws = (char*)d_ws;
    size_t off = 0;
    auto take = [&](size_t n) -> void* {
        void* p = ws + off;
        off = (off + n + 255) & ~(size_t)255;
        return p;
    };
    int*   bucketSlotStart = (int*)take((size_t)NB * 4);
    int*   cursor          = (int*)take((size_t)NB * 4);
    unsigned* ebuf         = (unsigned*)take((size_t)NB * BCAP * 4);
    int*   col_start       = (int*)take((size_t)(NN + 1) * 4);
    float* dinv            = (float*)take((size_t)NN * 4);
    int*   srcv            = (int*)take((size_t)TOT * 4);
    float* gsum            = (float*)take(HH * 4);
    float* gsq             = (float*)take(HH * 4);
    int*   gstart          = (int*)take(GG * 4);
    int*   gend            = (int*)take(GG * 4);
    float* poolsum         = (float*)take((size_t)GG * HH * 4);
    unsigned short* wt     = (unsigned short*)take((size_t)3 * HH * HH * 2);
    unsigned* Xbf          = (unsigned*)take((size_t)NN * 64 * 4);
    unsigned short* Abf    = (unsigned short*)take((size_t)NN * HH * 2);

    setup_kernel<<<(NN * 64 + 255) / 256, 256, 0, stream>>>(x, batch, Wl[0], Wl[1], Wl[2],
                                                            Xbf, cursor, gstart, gend, poolsum, wt);
    bfill2_kernel<<<(EE + FCHUNK - 1) / FCHUNK, 256, 0, stream>>>(ei, cursor, ebuf);
    bscan_kernel<<<1, 1024, 0, stream>>>(cursor, bucketSlotStart, col_start);
    bproc_kernel<<<NB, 256, 0, stream>>>(ebuf, cursor, bucketSlotStart, col_start, dinv, srcv);

    const int aggBlocks = (((NN + 1) / 2) * 64 + 255) / 256;   // 2 nodes per wave
    for (int l = 0; l < 3; ++l) {
        const unsigned short* W = wt + (size_t)l * HH * HH;
        agg_kernel<<<aggBlocks, 256, 0, stream>>>((const uint4*)Xbf, col_start, srcv,
                                                  dinv, Abf, gsum, gsq);
        gemm_stats_kernel<<<(NN + 127) / 128, 256, 0, stream>>>(Abf, W, bl[l], gsum, gsq);
        bnrelu_kernel<<<2048, 256, 0, stream>>>((const uint4*)Abf, bl[l], gsum, gsq,
                                                gl[l], betal[l], (uint4*)Xbf);
    }

    pool_kernel<<<dim3(GG, PSPLIT), 64, 0, stream>>>(Xbf, gstart, gend, poolsum);
    fc_kernel<<<GG, 128, 0, stream>>>(poolsum, gstart, gend, fc_w, fc_b, out);
}

// Round 6
// 560.011 us; speedup vs baseline: 1.3684x; 1.0299x over previous
//
#include <hip/hip_runtime.h>

#define NN 100000
#define EE 1600000
#define HH 128
#define GG 64
#define TOT (EE + NN)
#define PSPLIT 8
#define NB 782            // (NN+127)/128 buckets of 128 dst nodes
#define BCAP 4096         // fixed slots per bucket (mean 2046, sigma~45)
#define FCHUNK 4096       // edges per bfill2 block
#define GBLK ((NN + 255) / 256)   // 391 gemm blocks, BM=256

typedef __attribute__((ext_vector_type(8))) short s16x8;
typedef __attribute__((ext_vector_type(4))) float f32x4;

__device__ __forceinline__ unsigned short f2bf(float f) {
    unsigned u = __float_as_uint(f);
    u = u + 0x7FFFu + ((u >> 16) & 1u);   // round-to-nearest-even
    return (unsigned short)(u >> 16);
}

// ---------------- fused setup: cast + cursor/pool init + bounds(binsearch) + wprep ----------------

__global__ __launch_bounds__(256) void setup_kernel(const float* __restrict__ x,
                                                    const int* __restrict__ batch,
                                                    const float* __restrict__ W0,
                                                    const float* __restrict__ W1,
                                                    const float* __restrict__ W2,
                                                    unsigned* __restrict__ Xbf,
                                                    int* __restrict__ cursor,
                                                    int* __restrict__ gstart, int* __restrict__ gend,
                                                    float* __restrict__ poolsum,
                                                    unsigned short* __restrict__ Wt) {
    int i = blockIdx.x * 256 + threadIdx.x;
    if (i < NN * 64) {                        // cast x -> packed bf16
        float2 v = ((const float2*)x)[i];
        Xbf[i] = (unsigned)f2bf(v.x) | ((unsigned)f2bf(v.y) << 16);
    }
    if (i < NB) cursor[i] = i * BCAP;
    if (i < GG * HH) poolsum[i] = 0.f;
    if (i < GG) {                             // single-writer group bounds via binary search
        int lo = 0, hi = NN;
        while (lo < hi) { int m = (lo + hi) >> 1; if (batch[m] < i) lo = m + 1; else hi = m; }
        int s = lo;
        lo = 0; hi = NN;
        while (lo < hi) { int m = (lo + hi) >> 1; if (batch[m] < i + 1) lo = m + 1; else hi = m; }
        gstart[i] = s;
        gend[i] = lo;
    }
    if (i < 3 * HH * HH) {                    // W fp32 [k][n] -> bf16 [n][k]
        int l = i >> 14, r = i & 16383;
        const float* W = (l == 0) ? W0 : (l == 1) ? W1 : W2;
        int k = r >> 7, n = r & 127;
        Wt[l * HH * HH + n * HH + k] = f2bf(W[r]);
    }
}

// LDS-aggregated bucket scatter into fixed-capacity regions
__global__ __launch_bounds__(256) void bfill2_kernel(const int* __restrict__ ei, int* cursor,
                                                     unsigned* __restrict__ ebuf) {
    __shared__ int h[NB];
    __shared__ int lbase[NB];
    int tid = threadIdx.x;
    size_t e0 = (size_t)blockIdx.x * FCHUNK;
    for (int i = tid; i < NB; i += 256) h[i] = 0;
    __syncthreads();
    unsigned r[16], c[16];
#pragma unroll
    for (int k = 0; k < 16; ++k) {
        size_t e = e0 + (size_t)k * 256 + tid;
        unsigned rr = 0xFFFFFFFFu, cc = 0;
        if (e < EE) {
            rr = (unsigned)ei[e];
            cc = (unsigned)ei[EE + e];
            if (rr >= NN || cc >= NN) rr = 0xFFFFFFFFu;
        }
        r[k] = rr; c[k] = cc;
        if (rr != 0xFFFFFFFFu) atomicAdd(&h[cc >> 7], 1);
    }
    __syncthreads();
    for (int i = tid; i < NB; i += 256) {
        int cnt = h[i];
        lbase[i] = cnt ? atomicAdd(&cursor[i], cnt) : 0;
    }
    __syncthreads();
    for (int i = tid; i < NB; i += 256) h[i] = 0;
    __syncthreads();
#pragma unroll
    for (int k = 0; k < 16; ++k) {
        if (r[k] != 0xFFFFFFFFu) {
            unsigned cc = c[k];
            int b = cc >> 7;
            int slot = lbase[b] + atomicAdd(&h[b], 1);
            if (slot >= b * BCAP && slot < (b + 1) * BCAP)
                ebuf[slot] = (r[k] << 7) | (cc & 127u);
        }
    }
}

// scan over buckets: slot offsets (slots = edges + self-loops); counts from cursor
__global__ void bscan_kernel(const int* __restrict__ cursor, int* __restrict__ bucketSlotStart,
                             int* __restrict__ col_start) {
    __shared__ int ss[1024];
    int t = threadIdx.x;
    int ec = 0, nc = 0;
    if (t < NB) {
        ec = min(max(cursor[t] - t * BCAP, 0), BCAP);
        nc = min(128, NN - t * 128);
    }
    ss[t] = ec + nc;
    __syncthreads();
    for (int off = 1; off < 1024; off <<= 1) {
        int a = 0;
        if (t >= off) a = ss[t - off];
        __syncthreads();
        ss[t] += a;
        __syncthreads();
    }
    if (t < NB) bucketSlotStart[t] = ss[t] - (ec + nc);
    if (t == NB - 1) col_start[NN] = ss[t];
}

// one block per bucket: local count/scan in LDS, emit col_start/dinv/srcv sequentially
__global__ __launch_bounds__(256) void bproc_kernel(const unsigned* __restrict__ ebuf,
                                                    const int* __restrict__ cursor,
                                                    const int* __restrict__ bucketSlotStart,
                                                    int* __restrict__ col_start,
                                                    float* __restrict__ dinv,
                                                    int* __restrict__ srcv) {
    __shared__ unsigned s_e[BCAP];
    __shared__ int s_cnt[128], s_scan[128], s_cur[128];
    int b = blockIdx.x;
    int tid = threadIdx.x;
    int n0 = b * 128;
    int nb = min(128, NN - n0);
    int est = b * BCAP;
    int ecnt = min(max(cursor[b] - est, 0), BCAP);
    if (tid < 128) s_cnt[tid] = 0;
    __syncthreads();
    for (int i = tid; i < ecnt; i += 256) {
        unsigned v = ebuf[est + i];
        s_e[i] = v;
        atomicAdd(&s_cnt[v & 127u], 1);
    }
    __syncthreads();
    int myc = 0;
    if (tid < 128) {
        myc = (tid < nb) ? s_cnt[tid] + 1 : 0;   // +1 self-loop
        s_scan[tid] = myc;
    }
    __syncthreads();
    for (int off = 1; off < 128; off <<= 1) {
        int a = 0;
        if (tid < 128 && tid >= off) a = s_scan[tid - off];
        __syncthreads();
        if (tid < 128) s_scan[tid] += a;
        __syncthreads();
    }
    if (tid < nb) {
        int slotbase = bucketSlotStart[b] + s_scan[tid] - myc;
        col_start[n0 + tid] = slotbase;
        dinv[n0 + tid] = rsqrtf((float)(s_cnt[tid] + 1));
        srcv[slotbase] = n0 + tid;               // self-loop first
        s_cur[tid] = slotbase + 1;
    }
    __syncthreads();
    for (int i = tid; i < ecnt; i += 256) {
        unsigned v = s_e[i];
        int slot = atomicAdd(&s_cur[v & 127u], 1);
        srcv[slot] = (int)(v >> 7);
    }
}

// ---------------- per-layer kernels ----------------

// TWO dst nodes per wave (lanes 0-31 -> node 2w, lanes 32-63 -> node 2w+1).
// rounds padded to a multiple of 6 so every gather sits in a 6-deep pipelined
// batch (R2: -5% vs tail; latency partially hidden by TLP already).
__global__ __launch_bounds__(256) void agg_kernel(const uint4* __restrict__ Xbf4,
                                                  const int* __restrict__ col_start,
                                                  const int* __restrict__ srcv,
                                                  const float* __restrict__ dinv,
                                                  unsigned short* __restrict__ Abf,
                                                  float* __restrict__ gsum,
                                                  float* __restrict__ gsq) {
    if (blockIdx.x == 0 && threadIdx.x < HH) {
        gsum[threadIdx.x] = 0.f;
        gsq[threadIdx.x] = 0.f;
    }
    int wv = (int)((blockIdx.x * blockDim.x + threadIdx.x) >> 6);
    int lane = threadIdx.x & 63;
    int half = lane >> 5;
    int node = 2 * wv + half;
    if (2 * wv >= NN) return;
    bool valid = node < NN;
    int s0 = 0, s1 = 0;
    float dd = 0.f;
    if (valid) { s0 = col_start[node]; s1 = col_start[node + 1]; dd = dinv[node]; }
    int lane31 = lane & 31;
    int qh = (lane >> 4) & 1;     // quarter within half
    int l16 = lane & 15;          // 16 lanes cover one 256B row (uint4 each)
    float acc[8];
#pragma unroll
    for (int j = 0; j < 8; ++j) acc[j] = 0.f;

    for (int base = s0; base < s1; base += 32) {
        int cnt = min(32, s1 - base);
        int msrc = 0;
        float mw = 0.f;
        if (lane31 < cnt) { msrc = srcv[base + lane31]; mw = dinv[msrc] * dd; }
        int rounds = (cnt + 1) >> 1;
        int rp = ((rounds + 5) / 6) * 6;          // pad to full 6-batches
        for (int p = 0; p < rp; p += 6) {
            uint4 u[6];
            float w[6];
#pragma unroll
            for (int k = 0; k < 6; ++k) {
                int idx = (p + k) * 2 + qh;
                int sl = half * 32 + min(idx, 31);
                int src = __shfl(msrc, sl);
                float wk = __shfl(mw, sl);        // 0 beyond cnt (preload zeroed)
                if (idx > 31) wk = 0.f;           // clamped lanes: force dead weight
                w[k] = wk;
                u[k] = Xbf4[(size_t)src * 16 + l16];
            }
#pragma unroll
            for (int k = 0; k < 6; ++k) {
                acc[0] += w[k] * __uint_as_float(u[k].x << 16);
                acc[1] += w[k] * __uint_as_float(u[k].x & 0xFFFF0000u);
                acc[2] += w[k] * __uint_as_float(u[k].y << 16);
                acc[3] += w[k] * __uint_as_float(u[k].y & 0xFFFF0000u);
                acc[4] += w[k] * __uint_as_float(u[k].z << 16);
                acc[5] += w[k] * __uint_as_float(u[k].z & 0xFFFF0000u);
                acc[6] += w[k] * __uint_as_float(u[k].w << 16);
                acc[7] += w[k] * __uint_as_float(u[k].w & 0xFFFF0000u);
            }
        }
    }
#pragma unroll
    for (int j = 0; j < 8; ++j) acc[j] += __shfl_xor(acc[j], 16);   // combine the 2 quarters
    if ((lane & 16) == 0 && valid) {
        uint4 pk;
        pk.x = (unsigned)f2bf(acc[0]) | ((unsigned)f2bf(acc[1]) << 16);
        pk.y = (unsigned)f2bf(acc[2]) | ((unsigned)f2bf(acc[3]) << 16);
        pk.z = (unsigned)f2bf(acc[4]) | ((unsigned)f2bf(acc[5]) << 16);
        pk.w = (unsigned)f2bf(acc[6]) | ((unsigned)f2bf(acc[7]) << 16);
        ((uint4*)Abf)[(size_t)node * 16 + l16] = pk;
    }
}

// W staging: fragment-major [nt][ks][quad][mcol][8] so each wave's 64 lanes
// read 64 consecutive 16B chunks (conflict-free; R4 layout had 400K conflict-cyc).
__device__ __forceinline__ void stage_w_frag(unsigned short* wlds,
                                             const unsigned short* __restrict__ Wt, int tid) {
#pragma unroll
    for (int it = 0; it < 8; ++it) {
        int c = it * 256 + tid;
        int n = c & 127, k8 = c >> 7;
        int nt = n >> 4, mcol = n & 15, ks = k8 >> 2, quad = k8 & 3;
        int dst = (nt * 16 + ks * 4 + quad) * 16 + mcol;
        *(uint4*)&wlds[dst * 8] = *(const uint4*)(Wt + n * HH + k8 * 8);
    }
}

__device__ __forceinline__ void load_a(const unsigned short* __restrict__ Abf,
                                       int row0, int row1, s16x8* a0, s16x8* a1, int quad) {
    s16x8 zf = {0, 0, 0, 0, 0, 0, 0, 0};
#pragma unroll
    for (int ks = 0; ks < 4; ++ks) {
        int k0 = ks * 32 + quad * 8;
        a0[ks] = (row0 < NN) ? *(const s16x8*)(Abf + (size_t)row0 * HH + k0) : zf;
        a1[ks] = (row1 < NN) ? *(const s16x8*)(Abf + (size_t)row1 * HH + k0) : zf;
    }
}

// pass 1: MFMA product, BN column sum/sumsq only — H never materialized.
// BM=256 (two 128-row subtiles per block): half the block generations, W staged
// once per 256 rows; subtile-1 A-loads issued before subtile-0 epilogue so HBM
// latency hides under the reduction chains (R4 fused: GEMM phase is latency-bound,
// MfmaUtil~3% VALUBusy~12% during compute).
__global__ __launch_bounds__(256, 3) void gemm_stats_kernel(const unsigned short* __restrict__ Abf,
                                                            const unsigned short* __restrict__ Wt,
                                                            const float* __restrict__ bias,
                                                            float* __restrict__ gsum,
                                                            float* __restrict__ gsq) {
    __shared__ unsigned short wlds[2048 * 8];    // 32 KB fragment-major
    __shared__ float ssum[HH], ssq[HH];
    int tid = threadIdx.x;
    if (tid < HH) { ssum[tid] = 0.f; ssq[tid] = 0.f; }
    stage_w_frag(wlds, Wt, tid);

    int lane = tid & 63;
    int wave = tid >> 6;
    int mcol = lane & 15;
    int quad = lane >> 4;
    int rowbase0 = blockIdx.x * 256 + wave * 32;

    // prefetch subtile-0 A before the barrier (latency hides under W ds_writes+sync)
    s16x8 a0c[4], a1c[4], a0n[4], a1n[4];
    load_a(Abf, rowbase0 + mcol, rowbase0 + mcol + 16, a0c, a1c, quad);
    __syncthreads();

    float s[8], sq[8];
#pragma unroll
    for (int nt = 0; nt < 8; ++nt) { s[nt] = 0.f; sq[nt] = 0.f; }

#pragma unroll
    for (int sub = 0; sub < 2; ++sub) {
        int rowbase = rowbase0 + sub * 128;
        f32x4 acc[2][8];
#pragma unroll
        for (int mt = 0; mt < 2; ++mt)
#pragma unroll
            for (int nt = 0; nt < 8; ++nt) acc[mt][nt] = (f32x4){0.f, 0.f, 0.f, 0.f};
#pragma unroll
        for (int ks = 0; ks < 4; ++ks) {
#pragma unroll
            for (int nt = 0; nt < 8; ++nt) {
                s16x8 b = *(const s16x8*)&wlds[((nt * 16 + ks * 4 + quad) * 16 + mcol) * 8];
                acc[0][nt] = __builtin_amdgcn_mfma_f32_16x16x32_bf16(a0c[ks], b, acc[0][nt], 0, 0, 0);
                acc[1][nt] = __builtin_amdgcn_mfma_f32_16x16x32_bf16(a1c[ks], b, acc[1][nt], 0, 0, 0);
            }
        }
        if (sub == 0) {   // issue subtile-1 loads now; latency hides under epilogue
            load_a(Abf, rowbase0 + 128 + mcol, rowbase0 + 128 + mcol + 16, a0n, a1n, quad);
        }
        // epilogue: accumulate column sums/sumsq from live acc
#pragma unroll
        for (int mt = 0; mt < 2; ++mt) {
            int rbase = rowbase + mt * 16 + quad * 4;
#pragma unroll
            for (int nt = 0; nt < 8; ++nt) {
                float bv = bias[nt * 16 + mcol];
                f32x4 a = acc[mt][nt];
#pragma unroll
                for (int reg = 0; reg < 4; ++reg) {
                    if (rbase + reg < NN) {
                        float h = a[reg] + bv;
                        s[nt] += h; sq[nt] += h * h;
                    }
                }
            }
        }
        if (sub == 0) {
#pragma unroll
            for (int ks = 0; ks < 4; ++ks) { a0c[ks] = a0n[ks]; a1c[ks] = a1n[ks]; }
        }
    }

#pragma unroll
    for (int nt = 0; nt < 8; ++nt) {
        float v = s[nt];  v += __shfl_xor(v, 16);  v += __shfl_xor(v, 32);
        float w = sq[nt]; w += __shfl_xor(w, 16);  w += __shfl_xor(w, 32);
        if (quad == 0) {
            atomicAdd(&ssum[nt * 16 + mcol], v);
            atomicAdd(&ssq[nt * 16 + mcol], w);
        }
    }
    __syncthreads();
    if (tid < HH) {
        atomicAdd(&gsum[tid], ssum[tid]);
        atomicAdd(&gsq[tid], ssq[tid]);
    }
}

// pass 2: recompute MFMA product, apply bias+BN+ReLU, store bf16 X.
// Same BM=256 + prefetch structure as stats.
__global__ __launch_bounds__(256, 3) void gemm_apply_kernel(const unsigned short* __restrict__ Abf,
                                                            const unsigned short* __restrict__ Wt,
                                                            const float* __restrict__ bias,
                                                            const float* __restrict__ gsum,
                                                            const float* __restrict__ gsq,
                                                            const float* __restrict__ g,
                                                            const float* __restrict__ beta,
                                                            unsigned short* __restrict__ Xb16) {
    __shared__ unsigned short wlds[2048 * 8];
    __shared__ float asc[HH], bsh[HH];
    int tid = threadIdx.x;
    stage_w_frag(wlds, Wt, tid);
    if (tid < HH) {
        float mu = gsum[tid] * (1.f / (float)NN);
        float var = fmaxf(gsq[tid] * (1.f / (float)NN) - mu * mu, 0.f);
        float a = g[tid] * rsqrtf(var + 1e-5f);
        asc[tid] = a;
        bsh[tid] = a * (bias[tid] - mu) + beta[tid];   // o = a*acc + bsh (acc pre-bias)
    }

    int lane = tid & 63;
    int wave = tid >> 6;
    int mcol = lane & 15;
    int quad = lane >> 4;
    int rowbase0 = blockIdx.x * 256 + wave * 32;

    s16x8 a0c[4], a1c[4], a0n[4], a1n[4];
    load_a(Abf, rowbase0 + mcol, rowbase0 + mcol + 16, a0c, a1c, quad);
    __syncthreads();

#pragma unroll
    for (int sub = 0; sub < 2; ++sub) {
        int rowbase = rowbase0 + sub * 128;
        f32x4 acc[2][8];
#pragma unroll
        for (int mt = 0; mt < 2; ++mt)
#pragma unroll
            for (int nt = 0; nt < 8; ++nt) acc[mt][nt] = (f32x4){0.f, 0.f, 0.f, 0.f};
#pragma unroll
        for (int ks = 0; ks < 4; ++ks) {
#pragma unroll
            for (int nt = 0; nt < 8; ++nt) {
                s16x8 b = *(const s16x8*)&wlds[((nt * 16 + ks * 4 + quad) * 16 + mcol) * 8];
                acc[0][nt] = __builtin_amdgcn_mfma_f32_16x16x32_bf16(a0c[ks], b, acc[0][nt], 0, 0, 0);
                acc[1][nt] = __builtin_amdgcn_mfma_f32_16x16x32_bf16(a1c[ks], b, acc[1][nt], 0, 0, 0);
            }
        }
        if (sub == 0) {
            load_a(Abf, rowbase0 + 128 + mcol, rowbase0 + 128 + mcol + 16, a0n, a1n, quad);
        }
#pragma unroll
        for (int mt = 0; mt < 2; ++mt) {
            int rbase = rowbase + mt * 16 + quad * 4;
#pragma unroll
            for (int nt = 0; nt < 8; ++nt) {
                int col = nt * 16 + mcol;
                float av = asc[col], bv = bsh[col];
                f32x4 a = acc[mt][nt];
#pragma unroll
                for (int reg = 0; reg < 4; ++reg) {
                    int r = rbase + reg;
                    if (r < NN) {
                        float o = fmaxf(av * a[reg] + bv, 0.f);
                        Xb16[(size_t)r * HH + col] = f2bf(o);
                    }
                }
            }
        }
        if (sub == 0) {
#pragma unroll
            for (int ks = 0; ks < 4; ++ks) { a0c[ks] = a0n[ks]; a1c[ks] = a1n[ks]; }
        }
    }
}

// ---------------- pooling + fc ----------------

__global__ void pool_kernel(const unsigned* __restrict__ Xbf, const int* __restrict__ gstart,
                            const int* __restrict__ gend, float* __restrict__ poolsum) {
    int g = blockIdx.x;
    int sp = blockIdx.y;
    int t = threadIdx.x;           // 64: each handles 2 cols
    int s = gstart[g], e = gend[g];
    if (e <= s) return;
    int len = e - s;
    int chunk = (len + PSPLIT - 1) / PSPLIT;
    int cs = s + sp * chunk;
    int ce = min(cs + chunk, e);
    if (cs >= ce) return;
    float2 acc = make_float2(0.f, 0.f);
    for (int i = cs; i < ce; ++i) {
        unsigned u = Xbf[(size_t)i * 64 + t];
        acc.x += __uint_as_float(u << 16);
        acc.y += __uint_as_float(u & 0xFFFF0000u);
    }
    atomicAdd(&poolsum[g * HH + 2 * t], acc.x);
    atomicAdd(&poolsum[g * HH + 2 * t + 1], acc.y);
}

__global__ void fc_kernel(const float* __restrict__ poolsum, const int* __restrict__ gstart,
                          const int* __restrict__ gend, const float* __restrict__ fc_w,
                          const float* __restrict__ fc_b, float* __restrict__ out) {
    int g = blockIdx.x;
    int o = threadIdx.x;
    int cnt = gend[g] - gstart[g];
    float inv = (cnt > 0) ? (1.f / (float)cnt) : 0.f;
    float acc = fc_b[o];
    for (int k = 0; k < HH; ++k) acc += (poolsum[g * HH + k] * inv) * fc_w[k * HH + o];
    out[g * HH + o] = acc;
}

// ---------------- launch ----------------

extern "C" void kernel_launch(void* const* d_in, const int* in_sizes, int n_in,
                              void* d_out, int out_size, void* d_ws, size_t ws_size,
                              hipStream_t stream) {
    const float* x     = (const float*)d_in[0];
    const int*   ei    = (const int*)d_in[1];
    const int*   batch = (const int*)d_in[2];
    const float* Wl[3]    = {(const float*)d_in[3], (const float*)d_in[7], (const float*)d_in[11]};
    const float* bl[3]    = {(const float*)d_in[4], (const float*)d_in[8], (const float*)d_in[12]};
    const float* gl[3]    = {(const float*)d_in[5], (const float*)d_in[9], (const float*)d_in[13]};
    const float* betal[3] = {(const float*)d_in[6], (const float*)d_in[10], (const float*)d_in[14]};
    const float* fc_w = (const float*)d_in[15];
    const float* fc_b = (const float*)d_in[16];
    float* out = (float*)d_out;

    char* ws = (char*)d_ws;
    size_t off = 0;
    auto take = [&](size_t n) -> void* {
        void* p = ws + off;
        off = (off + n + 255) & ~(size_t)255;
        return p;
    };
    int*   bucketSlotStart = (int*)take((size_t)NB * 4);
    int*   cursor          = (int*)take((size_t)NB * 4);
    unsigned* ebuf         = (unsigned*)take((size_t)NB * BCAP * 4);
    int*   col_start       = (int*)take((size_t)(NN + 1) * 4);
    float* dinv            = (float*)take((size_t)NN * 4);
    int*   srcv            = (int*)take((size_t)TOT * 4);
    float* gsum            = (float*)take(HH * 4);
    float* gsq             = (float*)take(HH * 4);
    int*   gstart          = (int*)take(GG * 4);
    int*   gend            = (int*)take(GG * 4);
    float* poolsum         = (float*)take((size_t)GG * HH * 4);
    unsigned short* wt     = (unsigned short*)take((size_t)3 * HH * HH * 2);
    unsigned* Xbf          = (unsigned*)take((size_t)NN * 64 * 4);
    unsigned short* Abf    = (unsigned short*)take((size_t)NN * HH * 2);

    setup_kernel<<<(NN * 64 + 255) / 256, 256, 0, stream>>>(x, batch, Wl[0], Wl[1], Wl[2],
                                                            Xbf, cursor, gstart, gend, poolsum, wt);
    bfill2_kernel<<<(EE + FCHUNK - 1) / FCHUNK, 256, 0, stream>>>(ei, cursor, ebuf);
    bscan_kernel<<<1, 1024, 0, stream>>>(cursor, bucketSlotStart, col_start);
    bproc_kernel<<<NB, 256, 0, stream>>>(ebuf, cursor, bucketSlotStart, col_start, dinv, srcv);

    const int aggBlocks = (((NN + 1) / 2) * 64 + 255) / 256;   // 2 nodes per wave
    for (int l = 0; l < 3; ++l) {
        const unsigned short* W = wt + (size_t)l * HH * HH;
        agg_kernel<<<aggBlocks, 256, 0, stream>>>((const uint4*)Xbf, col_start, srcv,
                                                  dinv, Abf, gsum, gsq);
        gemm_stats_kernel<<<GBLK, 256, 0, stream>>>(Abf, W, bl[l], gsum, gsq);
        gemm_apply_kernel<<<GBLK, 256, 0, stream>>>(Abf, W, bl[l], gsum, gsq,
                                                    gl[l], betal[l], (unsigned short*)Xbf);
    }

    pool_kernel<<<dim3(GG, PSPLIT), 64, 0, stream>>>(Xbf, gstart, gend, poolsum);
    fc_kernel<<<GG, 128, 0, stream>>>(poolsum, gstart, gend, fc_w, fc_b, out);
}

// Round 7
// 558.920 us; speedup vs baseline: 1.3711x; 1.0020x over previous
//
#include <hip/hip_runtime.h>

#define NN 100000
#define EE 1600000
#define HH 128
#define GG 64
#define TOT (EE + NN)
#define PSPLIT 8
#define NB 782            // (NN+127)/128 buckets of 128 dst nodes
#define BCAP 4096         // fixed slots per bucket (mean 2046, sigma~45)
#define FCHUNK 4096       // edges per bfill2 block

typedef __attribute__((ext_vector_type(8))) short s16x8;
typedef __attribute__((ext_vector_type(4))) float f32x4;

__device__ __forceinline__ unsigned short f2bf(float f) {
    unsigned u = __float_as_uint(f);
    u = u + 0x7FFFu + ((u >> 16) & 1u);   // round-to-nearest-even
    return (unsigned short)(u >> 16);
}

// ---------------- fused setup: cast + cursor/pool init + bounds(binsearch) + wprep ----------------

__global__ __launch_bounds__(256) void setup_kernel(const float* __restrict__ x,
                                                    const int* __restrict__ batch,
                                                    const float* __restrict__ W0,
                                                    const float* __restrict__ W1,
                                                    const float* __restrict__ W2,
                                                    unsigned* __restrict__ Xbf,
                                                    int* __restrict__ cursor,
                                                    int* __restrict__ gstart, int* __restrict__ gend,
                                                    float* __restrict__ poolsum,
                                                    unsigned short* __restrict__ Wt) {
    int i = blockIdx.x * 256 + threadIdx.x;
    if (i < NN * 64) {                        // cast x -> packed bf16
        float2 v = ((const float2*)x)[i];
        Xbf[i] = (unsigned)f2bf(v.x) | ((unsigned)f2bf(v.y) << 16);
    }
    if (i < NB) cursor[i] = i * BCAP;
    if (i < GG * HH) poolsum[i] = 0.f;
    if (i < GG) {                             // single-writer group bounds via binary search
        int lo = 0, hi = NN;
        while (lo < hi) { int m = (lo + hi) >> 1; if (batch[m] < i) lo = m + 1; else hi = m; }
        int s = lo;
        lo = 0; hi = NN;
        while (lo < hi) { int m = (lo + hi) >> 1; if (batch[m] < i + 1) lo = m + 1; else hi = m; }
        gstart[i] = s;
        gend[i] = lo;
    }
    if (i < 3 * HH * HH) {                    // W fp32 [k][n] -> bf16 [n][k]
        int l = i >> 14, r = i & 16383;
        const float* W = (l == 0) ? W0 : (l == 1) ? W1 : W2;
        int k = r >> 7, n = r & 127;
        Wt[l * HH * HH + n * HH + k] = f2bf(W[r]);
    }
}

// LDS-aggregated bucket scatter into fixed-capacity regions
__global__ __launch_bounds__(256) void bfill2_kernel(const int* __restrict__ ei, int* cursor,
                                                     unsigned* __restrict__ ebuf) {
    __shared__ int h[NB];
    __shared__ int lbase[NB];
    int tid = threadIdx.x;
    size_t e0 = (size_t)blockIdx.x * FCHUNK;
    for (int i = tid; i < NB; i += 256) h[i] = 0;
    __syncthreads();
    unsigned r[16], c[16];
#pragma unroll
    for (int k = 0; k < 16; ++k) {
        size_t e = e0 + (size_t)k * 256 + tid;
        unsigned rr = 0xFFFFFFFFu, cc = 0;
        if (e < EE) {
            rr = (unsigned)ei[e];
            cc = (unsigned)ei[EE + e];
            if (rr >= NN || cc >= NN) rr = 0xFFFFFFFFu;
        }
        r[k] = rr; c[k] = cc;
        if (rr != 0xFFFFFFFFu) atomicAdd(&h[cc >> 7], 1);
    }
    __syncthreads();
    for (int i = tid; i < NB; i += 256) {
        int cnt = h[i];
        lbase[i] = cnt ? atomicAdd(&cursor[i], cnt) : 0;
    }
    __syncthreads();
    for (int i = tid; i < NB; i += 256) h[i] = 0;
    __syncthreads();
#pragma unroll
    for (int k = 0; k < 16; ++k) {
        if (r[k] != 0xFFFFFFFFu) {
            unsigned cc = c[k];
            int b = cc >> 7;
            int slot = lbase[b] + atomicAdd(&h[b], 1);
            if (slot >= b * BCAP && slot < (b + 1) * BCAP)
                ebuf[slot] = (r[k] << 7) | (cc & 127u);
        }
    }
}

// scan over buckets: slot offsets (slots = edges + self-loops); counts from cursor
__global__ void bscan_kernel(const int* __restrict__ cursor, int* __restrict__ bucketSlotStart,
                             int* __restrict__ col_start) {
    __shared__ int ss[1024];
    int t = threadIdx.x;
    int ec = 0, nc = 0;
    if (t < NB) {
        ec = min(max(cursor[t] - t * BCAP, 0), BCAP);
        nc = min(128, NN - t * 128);
    }
    ss[t] = ec + nc;
    __syncthreads();
    for (int off = 1; off < 1024; off <<= 1) {
        int a = 0;
        if (t >= off) a = ss[t - off];
        __syncthreads();
        ss[t] += a;
        __syncthreads();
    }
    if (t < NB) bucketSlotStart[t] = ss[t] - (ec + nc);
    if (t == NB - 1) col_start[NN] = ss[t];
}

// one block per bucket: local count/scan in LDS, emit col_start/dinv/srcv sequentially
__global__ __launch_bounds__(256) void bproc_kernel(const unsigned* __restrict__ ebuf,
                                                    const int* __restrict__ cursor,
                                                    const int* __restrict__ bucketSlotStart,
                                                    int* __restrict__ col_start,
                                                    float* __restrict__ dinv,
                                                    int* __restrict__ srcv) {
    __shared__ unsigned s_e[BCAP];
    __shared__ int s_cnt[128], s_scan[128], s_cur[128];
    int b = blockIdx.x;
    int tid = threadIdx.x;
    int n0 = b * 128;
    int nb = min(128, NN - n0);
    int est = b * BCAP;
    int ecnt = min(max(cursor[b] - est, 0), BCAP);
    if (tid < 128) s_cnt[tid] = 0;
    __syncthreads();
    for (int i = tid; i < ecnt; i += 256) {
        unsigned v = ebuf[est + i];
        s_e[i] = v;
        atomicAdd(&s_cnt[v & 127u], 1);
    }
    __syncthreads();
    int myc = 0;
    if (tid < 128) {
        myc = (tid < nb) ? s_cnt[tid] + 1 : 0;   // +1 self-loop
        s_scan[tid] = myc;
    }
    __syncthreads();
    for (int off = 1; off < 128; off <<= 1) {
        int a = 0;
        if (tid < 128 && tid >= off) a = s_scan[tid - off];
        __syncthreads();
        if (tid < 128) s_scan[tid] += a;
        __syncthreads();
    }
    if (tid < nb) {
        int slotbase = bucketSlotStart[b] + s_scan[tid] - myc;
        col_start[n0 + tid] = slotbase;
        dinv[n0 + tid] = rsqrtf((float)(s_cnt[tid] + 1));
        srcv[slotbase] = n0 + tid;               // self-loop first
        s_cur[tid] = slotbase + 1;
    }
    __syncthreads();
    for (int i = tid; i < ecnt; i += 256) {
        unsigned v = s_e[i];
        int slot = atomicAdd(&s_cur[v & 127u], 1);
        srcv[slot] = (int)(v >> 7);
    }
}

// ---------------- per-layer kernels ----------------

// TWO dst nodes per wave (lanes 0-31 -> node 2w, lanes 32-63 -> node 2w+1).
// rounds padded to a multiple of 6 so every gather sits in a 6-deep pipelined
// batch (R2: -5% vs tail; latency partially hidden by TLP already).
__global__ __launch_bounds__(256) void agg_kernel(const uint4* __restrict__ Xbf4,
                                                  const int* __restrict__ col_start,
                                                  const int* __restrict__ srcv,
                                                  const float* __restrict__ dinv,
                                                  unsigned short* __restrict__ Abf,
                                                  float* __restrict__ gsum,
                                                  float* __restrict__ gsq) {
    if (blockIdx.x == 0 && threadIdx.x < HH) {
        gsum[threadIdx.x] = 0.f;
        gsq[threadIdx.x] = 0.f;
    }
    int wv = (int)((blockIdx.x * blockDim.x + threadIdx.x) >> 6);
    int lane = threadIdx.x & 63;
    int half = lane >> 5;
    int node = 2 * wv + half;
    if (2 * wv >= NN) return;
    bool valid = node < NN;
    int s0 = 0, s1 = 0;
    float dd = 0.f;
    if (valid) { s0 = col_start[node]; s1 = col_start[node + 1]; dd = dinv[node]; }
    int lane31 = lane & 31;
    int qh = (lane >> 4) & 1;     // quarter within half
    int l16 = lane & 15;          // 16 lanes cover one 256B row (uint4 each)
    float acc[8];
#pragma unroll
    for (int j = 0; j < 8; ++j) acc[j] = 0.f;

    for (int base = s0; base < s1; base += 32) {
        int cnt = min(32, s1 - base);
        int msrc = 0;
        float mw = 0.f;
        if (lane31 < cnt) { msrc = srcv[base + lane31]; mw = dinv[msrc] * dd; }
        int rounds = (cnt + 1) >> 1;
        int rp = ((rounds + 5) / 6) * 6;          // pad to full 6-batches
        for (int p = 0; p < rp; p += 6) {
            uint4 u[6];
            float w[6];
#pragma unroll
            for (int k = 0; k < 6; ++k) {
                int idx = (p + k) * 2 + qh;
                int sl = half * 32 + min(idx, 31);
                int src = __shfl(msrc, sl);
                float wk = __shfl(mw, sl);        // 0 beyond cnt (preload zeroed)
                if (idx > 31) wk = 0.f;           // clamped lanes: force dead weight
                w[k] = wk;
                u[k] = Xbf4[(size_t)src * 16 + l16];
            }
#pragma unroll
            for (int k = 0; k < 6; ++k) {
                acc[0] += w[k] * __uint_as_float(u[k].x << 16);
                acc[1] += w[k] * __uint_as_float(u[k].x & 0xFFFF0000u);
                acc[2] += w[k] * __uint_as_float(u[k].y << 16);
                acc[3] += w[k] * __uint_as_float(u[k].y & 0xFFFF0000u);
                acc[4] += w[k] * __uint_as_float(u[k].z << 16);
                acc[5] += w[k] * __uint_as_float(u[k].z & 0xFFFF0000u);
                acc[6] += w[k] * __uint_as_float(u[k].w << 16);
                acc[7] += w[k] * __uint_as_float(u[k].w & 0xFFFF0000u);
            }
        }
    }
#pragma unroll
    for (int j = 0; j < 8; ++j) acc[j] += __shfl_xor(acc[j], 16);   // combine the 2 quarters
    if ((lane & 16) == 0 && valid) {
        uint4 pk;
        pk.x = (unsigned)f2bf(acc[0]) | ((unsigned)f2bf(acc[1]) << 16);
        pk.y = (unsigned)f2bf(acc[2]) | ((unsigned)f2bf(acc[3]) << 16);
        pk.z = (unsigned)f2bf(acc[4]) | ((unsigned)f2bf(acc[5]) << 16);
        pk.w = (unsigned)f2bf(acc[6]) | ((unsigned)f2bf(acc[7]) << 16);
        ((uint4*)Abf)[(size_t)node * 16 + l16] = pk;
    }
}

// W staging: fragment-major [nt][ks][quad][mcol][8] so each wave's 64 lanes
// read 64 consecutive 16B chunks (conflict-free; verified correct in R6).
__device__ __forceinline__ void stage_w_frag(unsigned short* wlds,
                                             const unsigned short* __restrict__ Wt, int tid) {
#pragma unroll
    for (int it = 0; it < 8; ++it) {
        int c = it * 256 + tid;
        int n = c & 127, k8 = c >> 7;
        int nt = n >> 4, mcol = n & 15, ks = k8 >> 2, quad = k8 & 3;
        int dst = (nt * 16 + ks * 4 + quad) * 16 + mcol;
        *(uint4*)&wlds[dst * 8] = *(const uint4*)(Wt + n * HH + k8 * 8);
    }
}

// GEMM + BN-stats; stores pre-bias H (bf16) IN PLACE over Abf via LDS transpose
// so the global stores are full uint4 coalesced lines (R5's 64 scalar 2B strided
// stores per thread were the regression; numerics of the H-store path are
// R5-verified: absmax 0.0078 vs threshold 0.0231).
// BM=128 (782 blocks, ~3/CU — R6 showed BM=256's 391 blocks starves TLP).
__global__ __launch_bounds__(256) void gemm_stats_kernel(unsigned short* __restrict__ Abf,
                                                         const unsigned short* __restrict__ Wt,
                                                         const float* __restrict__ bias,
                                                         float* __restrict__ gsum,
                                                         float* __restrict__ gsq) {
    __shared__ unsigned short shmem[128 * 136];  // union: W frag-major (16384 sh) | H tile [128][136]
    __shared__ float ssum[HH], ssq[HH];
    int tid = threadIdx.x;
    if (tid < HH) { ssum[tid] = 0.f; ssq[tid] = 0.f; }
    stage_w_frag(shmem, Wt, tid);

    int lane = tid & 63;
    int wave = tid >> 6;
    int mcol = lane & 15;
    int quad = lane >> 4;
    int rowbase = blockIdx.x * 128 + wave * 32;
    int row0 = rowbase + mcol;
    int row1 = row0 + 16;

    // A-fragment loads issued before the barrier (hide under W ds_writes + sync)
    s16x8 zf = {0, 0, 0, 0, 0, 0, 0, 0};
    s16x8 a0[4], a1[4];
#pragma unroll
    for (int ks = 0; ks < 4; ++ks) {
        int k0 = ks * 32 + quad * 8;
        a0[ks] = (row0 < NN) ? *(const s16x8*)(Abf + (size_t)row0 * HH + k0) : zf;
        a1[ks] = (row1 < NN) ? *(const s16x8*)(Abf + (size_t)row1 * HH + k0) : zf;
    }
    __syncthreads();

    f32x4 acc[2][8];
#pragma unroll
    for (int mt = 0; mt < 2; ++mt)
#pragma unroll
        for (int nt = 0; nt < 8; ++nt) acc[mt][nt] = (f32x4){0.f, 0.f, 0.f, 0.f};
#pragma unroll
    for (int ks = 0; ks < 4; ++ks) {
#pragma unroll
        for (int nt = 0; nt < 8; ++nt) {
            s16x8 b = *(const s16x8*)&shmem[((nt * 16 + ks * 4 + quad) * 16 + mcol) * 8];
            acc[0][nt] = __builtin_amdgcn_mfma_f32_16x16x32_bf16(a0[ks], b, acc[0][nt], 0, 0, 0);
            acc[1][nt] = __builtin_amdgcn_mfma_f32_16x16x32_bf16(a1[ks], b, acc[1][nt], 0, 0, 0);
        }
    }
    __syncthreads();   // all W reads done before H tile overwrites shmem

    // ---- BN stats (fp32, pre-rounding) + pack H bf16 into LDS [row][col] ----
    float s[8], sq[8];
#pragma unroll
    for (int nt = 0; nt < 8; ++nt) { s[nt] = 0.f; sq[nt] = 0.f; }
#pragma unroll
    for (int mt = 0; mt < 2; ++mt) {
#pragma unroll
        for (int nt = 0; nt < 8; ++nt) {
            float bv = bias[nt * 16 + mcol];
            f32x4 a = acc[mt][nt];
#pragma unroll
            for (int reg = 0; reg < 4; ++reg) {
                int rL = wave * 32 + mt * 16 + quad * 4 + reg;   // row in 128-tile
                if (blockIdx.x * 128 + rL < NN) {
                    float h = a[reg] + bv;
                    s[nt] += h; sq[nt] += h * h;
                }
                // pack 2 adjacent cols (mcol even gets partner from mcol+1)
                unsigned b16 = f2bf(a[reg]);
                unsigned other = (unsigned)__shfl_xor((int)b16, 1);
                if ((mcol & 1) == 0)
                    *(unsigned*)&shmem[rL * 136 + nt * 16 + mcol] = b16 | (other << 16);
            }
        }
    }
#pragma unroll
    for (int nt = 0; nt < 8; ++nt) {
        float v = s[nt];  v += __shfl_xor(v, 16);  v += __shfl_xor(v, 32);
        float w = sq[nt]; w += __shfl_xor(w, 16);  w += __shfl_xor(w, 32);
        if (quad == 0) {
            atomicAdd(&ssum[nt * 16 + mcol], v);
            atomicAdd(&ssq[nt * 16 + mcol], w);
        }
    }
    __syncthreads();   // H tile + ssum complete

    // ---- coalesced in-place H store: 2 threads per 256B row, uint4 lines ----
    {
        int rL = tid >> 1;
        int rG = blockIdx.x * 128 + rL;
        if (rG < NN) {
            int cb = (tid & 1) * 64;             // col base (bf16 units)
#pragma unroll
            for (int j = 0; j < 8; ++j) {
                uint4 v = *(const uint4*)&shmem[rL * 136 + cb + j * 8];
                ((uint4*)Abf)[(size_t)rG * 16 + (tid & 1) * 8 + j] = v;
            }
        }
    }
    if (tid < HH) {
        atomicAdd(&gsum[tid], ssum[tid]);
        atomicAdd(&gsq[tid], ssq[tid]);
    }
}

// elementwise BN+ReLU: X = relu(a*H + bsh), H read from Abf (bf16, pre-bias).
// Pure streaming pass replacing the MFMA-recompute apply kernel (R5-verified).
__global__ __launch_bounds__(256) void bnrelu_kernel(const uint4* __restrict__ Hb,
                                                     const float* __restrict__ bias,
                                                     const float* __restrict__ gsum,
                                                     const float* __restrict__ gsq,
                                                     const float* __restrict__ g,
                                                     const float* __restrict__ beta,
                                                     uint4* __restrict__ Xbf) {
    __shared__ float asc[HH], bsh[HH];
    int tid = threadIdx.x;
    if (tid < HH) {
        float mu = gsum[tid] * (1.f / (float)NN);
        float var = fmaxf(gsq[tid] * (1.f / (float)NN) - mu * mu, 0.f);
        float a = g[tid] * rsqrtf(var + 1e-5f);
        asc[tid] = a;
        bsh[tid] = a * (bias[tid] - mu) + beta[tid];   // o = a*h + bsh (h pre-bias)
    }
    __syncthreads();
    int stride = gridDim.x * 256;
    for (int e = blockIdx.x * 256 + tid; e < NN * 16; e += stride) {
        uint4 u = Hb[e];
        int c0 = (e & 15) * 8;
        uint4 o;
        float h0, h1, o0, o1;
        h0 = __uint_as_float(u.x << 16);  h1 = __uint_as_float(u.x & 0xFFFF0000u);
        o0 = fmaxf(fmaf(asc[c0 + 0], h0, bsh[c0 + 0]), 0.f);
        o1 = fmaxf(fmaf(asc[c0 + 1], h1, bsh[c0 + 1]), 0.f);
        o.x = (unsigned)f2bf(o0) | ((unsigned)f2bf(o1) << 16);
        h0 = __uint_as_float(u.y << 16);  h1 = __uint_as_float(u.y & 0xFFFF0000u);
        o0 = fmaxf(fmaf(asc[c0 + 2], h0, bsh[c0 + 2]), 0.f);
        o1 = fmaxf(fmaf(asc[c0 + 3], h1, bsh[c0 + 3]), 0.f);
        o.y = (unsigned)f2bf(o0) | ((unsigned)f2bf(o1) << 16);
        h0 = __uint_as_float(u.z << 16);  h1 = __uint_as_float(u.z & 0xFFFF0000u);
        o0 = fmaxf(fmaf(asc[c0 + 4], h0, bsh[c0 + 4]), 0.f);
        o1 = fmaxf(fmaf(asc[c0 + 5], h1, bsh[c0 + 5]), 0.f);
        o.z = (unsigned)f2bf(o0) | ((unsigned)f2bf(o1) << 16);
        h0 = __uint_as_float(u.w << 16);  h1 = __uint_as_float(u.w & 0xFFFF0000u);
        o0 = fmaxf(fmaf(asc[c0 + 6], h0, bsh[c0 + 6]), 0.f);
        o1 = fmaxf(fmaf(asc[c0 + 7], h1, bsh[c0 + 7]), 0.f);
        o.w = (unsigned)f2bf(o0) | ((unsigned)f2bf(o1) << 16);
        Xbf[e] = o;
    }
}

// ---------------- pooling + fc ----------------

__global__ void pool_kernel(const unsigned* __restrict__ Xbf, const int* __restrict__ gstart,
                            const int* __restrict__ gend, float* __restrict__ poolsum) {
    int g = blockIdx.x;
    int sp = blockIdx.y;
    int t = threadIdx.x;           // 64: each handles 2 cols
    int s = gstart[g], e = gend[g];
    if (e <= s) return;
    int len = e - s;
    int chunk = (len + PSPLIT - 1) / PSPLIT;
    int cs = s + sp * chunk;
    int ce = min(cs + chunk, e);
    if (cs >= ce) return;
    float2 acc = make_float2(0.f, 0.f);
    for (int i = cs; i < ce; ++i) {
        unsigned u = Xbf[(size_t)i * 64 + t];
        acc.x += __uint_as_float(u << 16);
        acc.y += __uint_as_float(u & 0xFFFF0000u);
    }
    atomicAdd(&poolsum[g * HH + 2 * t], acc.x);
    atomicAdd(&poolsum[g * HH + 2 * t + 1], acc.y);
}

__global__ void fc_kernel(const float* __restrict__ poolsum, const int* __restrict__ gstart,
                          const int* __restrict__ gend, const float* __restrict__ fc_w,
                          const float* __restrict__ fc_b, float* __restrict__ out) {
    int g = blockIdx.x;
    int o = threadIdx.x;
    int cnt = gend[g] - gstart[g];
    float inv = (cnt > 0) ? (1.f / (float)cnt) : 0.f;
    float acc = fc_b[o];
    for (int k = 0; k < HH; ++k) acc += (poolsum[g * HH + k] * inv) * fc_w[k * HH + o];
    out[g * HH + o] = acc;
}

// ---------------- launch ----------------

extern "C" void kernel_launch(void* const* d_in, const int* in_sizes, int n_in,
                              void* d_out, int out_size, void* d_ws, size_t ws_size,
                              hipStream_t stream) {
    const float* x     = (const float*)d_in[0];
    const int*   ei    = (const int*)d_in[1];
    const int*   batch = (const int*)d_in[2];
    const float* Wl[3]    = {(const float*)d_in[3], (const float*)d_in[7], (const float*)d_in[11]};
    const float* bl[3]    = {(const float*)d_in[4], (const float*)d_in[8], (const float*)d_in[12]};
    const float* gl[3]    = {(const float*)d_in[5], (const float*)d_in[9], (const float*)d_in[13]};
    const float* betal[3] = {(const float*)d_in[6], (const float*)d_in[10], (const float*)d_in[14]};
    const float* fc_w = (const float*)d_in[15];
    const float* fc_b = (const float*)d_in[16];
    float* out = (float*)d_out;

    char* ws = (char*)d_ws;
    size_t off = 0;
    auto take = [&](size_t n) -> void* {
        void* p = ws + off;
        off = (off + n + 255) & ~(size_t)255;
        return p;
    };
    int*   bucketSlotStart = (int*)take((size_t)NB * 4);
    int*   cursor          = (int*)take((size_t)NB * 4);
    unsigned* ebuf         = (unsigned*)take((size_t)NB * BCAP * 4);
    int*   col_start       = (int*)take((size_t)(NN + 1) * 4);
    float* dinv            = (float*)take((size_t)NN * 4);
    int*   srcv            = (int*)take((size_t)TOT * 4);
    float* gsum            = (float*)take(HH * 4);
    float* gsq             = (float*)take(HH * 4);
    int*   gstart          = (int*)take(GG * 4);
    int*   gend            = (int*)take(GG * 4);
    float* poolsum         = (float*)take((size_t)GG * HH * 4);
    unsigned short* wt     = (unsigned short*)take((size_t)3 * HH * HH * 2);
    unsigned* Xbf          = (unsigned*)take((size_t)NN * 64 * 4);
    unsigned short* Abf    = (unsigned short*)take((size_t)NN * HH * 2);

    setup_kernel<<<(NN * 64 + 255) / 256, 256, 0, stream>>>(x, batch, Wl[0], Wl[1], Wl[2],
                                                            Xbf, cursor, gstart, gend, poolsum, wt);
    bfill2_kernel<<<(EE + FCHUNK - 1) / FCHUNK, 256, 0, stream>>>(ei, cursor, ebuf);
    bscan_kernel<<<1, 1024, 0, stream>>>(cursor, bucketSlotStart, col_start);
    bproc_kernel<<<NB, 256, 0, stream>>>(ebuf, cursor, bucketSlotStart, col_start, dinv, srcv);

    const int aggBlocks = (((NN + 1) / 2) * 64 + 255) / 256;   // 2 nodes per wave
    for (int l = 0; l < 3; ++l) {
        const unsigned short* W = wt + (size_t)l * HH * HH;
        agg_kernel<<<aggBlocks, 256, 0, stream>>>((const uint4*)Xbf, col_start, srcv,
                                                  dinv, Abf, gsum, gsq);
        gemm_stats_kernel<<<(NN + 127) / 128, 256, 0, stream>>>(Abf, W, bl[l], gsum, gsq);
        bnrelu_kernel<<<2048, 256, 0, stream>>>((const uint4*)Abf, bl[l], gsum, gsq,
                                                gl[l], betal[l], (uint4*)Xbf);
    }

    pool_kernel<<<dim3(GG, PSPLIT), 64, 0, stream>>>(Xbf, gstart, gend, poolsum);
    fc_kernel<<<GG, 128, 0, stream>>>(poolsum, gstart, gend, fc_w, fc_b, out);
}

// Round 8
// 550.253 us; speedup vs baseline: 1.3927x; 1.0158x over previous
//
#include <hip/hip_runtime.h>

#define NN 100000
#define EE 1600000
#define HH 128
#define GG 64
#define TOT (EE + NN)
#define PSPLIT 8
#define NB 782            // (NN+127)/128 buckets of 128 dst nodes
#define BCAP 4096         // fixed slots per bucket (mean 2046, sigma~45)
#define FCHUNK 4096       // edges per bfill2 block

typedef __attribute__((ext_vector_type(8))) short s16x8;
typedef __attribute__((ext_vector_type(4))) float f32x4;

__device__ __forceinline__ unsigned short f2bf(float f) {
    unsigned u = __float_as_uint(f);
    u = u + 0x7FFFu + ((u >> 16) & 1u);   // round-to-nearest-even
    return (unsigned short)(u >> 16);
}

// ---------------- fused setup: cast + cursor/pool init + bounds(binsearch) + wprep ----------------

__global__ __launch_bounds__(256) void setup_kernel(const float* __restrict__ x,
                                                    const int* __restrict__ batch,
                                                    const float* __restrict__ W0,
                                                    const float* __restrict__ W1,
                                                    const float* __restrict__ W2,
                                                    unsigned* __restrict__ Xbf,
                                                    int* __restrict__ cursor,
                                                    int* __restrict__ gstart, int* __restrict__ gend,
                                                    float* __restrict__ poolsum,
                                                    unsigned short* __restrict__ Wt) {
    int i = blockIdx.x * 256 + threadIdx.x;
    if (i < NN * 64) {                        // cast x -> packed bf16
        float2 v = ((const float2*)x)[i];
        Xbf[i] = (unsigned)f2bf(v.x) | ((unsigned)f2bf(v.y) << 16);
    }
    if (i < NB) cursor[i] = i * BCAP;
    if (i < GG * HH) poolsum[i] = 0.f;
    if (i < GG) {                             // single-writer group bounds via binary search
        int lo = 0, hi = NN;
        while (lo < hi) { int m = (lo + hi) >> 1; if (batch[m] < i) lo = m + 1; else hi = m; }
        int s = lo;
        lo = 0; hi = NN;
        while (lo < hi) { int m = (lo + hi) >> 1; if (batch[m] < i + 1) lo = m + 1; else hi = m; }
        gstart[i] = s;
        gend[i] = lo;
    }
    if (i < 3 * HH * HH) {                    // W fp32 [k][n] -> bf16 FRAGMENT-MAJOR
        // chunk ((nt*16+ks*4+quad)*16+mcol), elem k&7 — the R6/R7-verified LDS
        // layout relocated to global so GEMM kernels read B straight from L2:
        // for fixed (nt,ks) the 64 lanes (mcol,quad) hit 64 consecutive 16B chunks.
        int l = i >> 14, r = i & 16383;
        const float* W = (l == 0) ? W0 : (l == 1) ? W1 : W2;
        int k = r >> 7, n = r & 127;
        int dst = ((((n >> 4) * 16 + (k >> 5) * 4 + ((k >> 3) & 3)) * 16) + (n & 15)) * 8 + (k & 7);
        Wt[l * HH * HH + dst] = f2bf(W[r]);
    }
}

// LDS-aggregated bucket scatter into fixed-capacity regions
__global__ __launch_bounds__(256) void bfill2_kernel(const int* __restrict__ ei, int* cursor,
                                                     unsigned* __restrict__ ebuf) {
    __shared__ int h[NB];
    __shared__ int lbase[NB];
    int tid = threadIdx.x;
    size_t e0 = (size_t)blockIdx.x * FCHUNK;
    for (int i = tid; i < NB; i += 256) h[i] = 0;
    __syncthreads();
    unsigned r[16], c[16];
#pragma unroll
    for (int k = 0; k < 16; ++k) {
        size_t e = e0 + (size_t)k * 256 + tid;
        unsigned rr = 0xFFFFFFFFu, cc = 0;
        if (e < EE) {
            rr = (unsigned)ei[e];
            cc = (unsigned)ei[EE + e];
            if (rr >= NN || cc >= NN) rr = 0xFFFFFFFFu;
        }
        r[k] = rr; c[k] = cc;
        if (rr != 0xFFFFFFFFu) atomicAdd(&h[cc >> 7], 1);
    }
    __syncthreads();
    for (int i = tid; i < NB; i += 256) {
        int cnt = h[i];
        lbase[i] = cnt ? atomicAdd(&cursor[i], cnt) : 0;
    }
    __syncthreads();
    for (int i = tid; i < NB; i += 256) h[i] = 0;
    __syncthreads();
#pragma unroll
    for (int k = 0; k < 16; ++k) {
        if (r[k] != 0xFFFFFFFFu) {
            unsigned cc = c[k];
            int b = cc >> 7;
            int slot = lbase[b] + atomicAdd(&h[b], 1);
            if (slot >= b * BCAP && slot < (b + 1) * BCAP)
                ebuf[slot] = (r[k] << 7) | (cc & 127u);
        }
    }
}

// scan over buckets: slot offsets (slots = edges + self-loops); counts from cursor
__global__ void bscan_kernel(const int* __restrict__ cursor, int* __restrict__ bucketSlotStart,
                             int* __restrict__ col_start) {
    __shared__ int ss[1024];
    int t = threadIdx.x;
    int ec = 0, nc = 0;
    if (t < NB) {
        ec = min(max(cursor[t] - t * BCAP, 0), BCAP);
        nc = min(128, NN - t * 128);
    }
    ss[t] = ec + nc;
    __syncthreads();
    for (int off = 1; off < 1024; off <<= 1) {
        int a = 0;
        if (t >= off) a = ss[t - off];
        __syncthreads();
        ss[t] += a;
        __syncthreads();
    }
    if (t < NB) bucketSlotStart[t] = ss[t] - (ec + nc);
    if (t == NB - 1) col_start[NN] = ss[t];
}

// one block per bucket: local count/scan in LDS, emit col_start/dinv/srcv sequentially
__global__ __launch_bounds__(256) void bproc_kernel(const unsigned* __restrict__ ebuf,
                                                    const int* __restrict__ cursor,
                                                    const int* __restrict__ bucketSlotStart,
                                                    int* __restrict__ col_start,
                                                    float* __restrict__ dinv,
                                                    int* __restrict__ srcv) {
    __shared__ unsigned s_e[BCAP];
    __shared__ int s_cnt[128], s_scan[128], s_cur[128];
    int b = blockIdx.x;
    int tid = threadIdx.x;
    int n0 = b * 128;
    int nb = min(128, NN - n0);
    int est = b * BCAP;
    int ecnt = min(max(cursor[b] - est, 0), BCAP);
    if (tid < 128) s_cnt[tid] = 0;
    __syncthreads();
    for (int i = tid; i < ecnt; i += 256) {
        unsigned v = ebuf[est + i];
        s_e[i] = v;
        atomicAdd(&s_cnt[v & 127u], 1);
    }
    __syncthreads();
    int myc = 0;
    if (tid < 128) {
        myc = (tid < nb) ? s_cnt[tid] + 1 : 0;   // +1 self-loop
        s_scan[tid] = myc;
    }
    __syncthreads();
    for (int off = 1; off < 128; off <<= 1) {
        int a = 0;
        if (tid < 128 && tid >= off) a = s_scan[tid - off];
        __syncthreads();
        if (tid < 128) s_scan[tid] += a;
        __syncthreads();
    }
    if (tid < nb) {
        int slotbase = bucketSlotStart[b] + s_scan[tid] - myc;
        col_start[n0 + tid] = slotbase;
        dinv[n0 + tid] = rsqrtf((float)(s_cnt[tid] + 1));
        srcv[slotbase] = n0 + tid;               // self-loop first
        s_cur[tid] = slotbase + 1;
    }
    __syncthreads();
    for (int i = tid; i < ecnt; i += 256) {
        unsigned v = s_e[i];
        int slot = atomicAdd(&s_cur[v & 127u], 1);
        srcv[slot] = (int)(v >> 7);
    }
}

// ---------------- per-layer kernels ----------------

// TWO dst nodes per wave (lanes 0-31 -> node 2w, lanes 32-63 -> node 2w+1).
// rounds padded to a multiple of 6 so every gather sits in a 6-deep pipelined
// batch (R2: -5% vs tail; latency partially hidden by TLP already).
__global__ __launch_bounds__(256) void agg_kernel(const uint4* __restrict__ Xbf4,
                                                  const int* __restrict__ col_start,
                                                  const int* __restrict__ srcv,
                                                  const float* __restrict__ dinv,
                                                  unsigned short* __restrict__ Abf,
                                                  float* __restrict__ gsum,
                                                  float* __restrict__ gsq) {
    if (blockIdx.x == 0 && threadIdx.x < HH) {
        gsum[threadIdx.x] = 0.f;
        gsq[threadIdx.x] = 0.f;
    }
    int wv = (int)((blockIdx.x * blockDim.x + threadIdx.x) >> 6);
    int lane = threadIdx.x & 63;
    int half = lane >> 5;
    int node = 2 * wv + half;
    if (2 * wv >= NN) return;
    bool valid = node < NN;
    int s0 = 0, s1 = 0;
    float dd = 0.f;
    if (valid) { s0 = col_start[node]; s1 = col_start[node + 1]; dd = dinv[node]; }
    int lane31 = lane & 31;
    int qh = (lane >> 4) & 1;     // quarter within half
    int l16 = lane & 15;          // 16 lanes cover one 256B row (uint4 each)
    float acc[8];
#pragma unroll
    for (int j = 0; j < 8; ++j) acc[j] = 0.f;

    for (int base = s0; base < s1; base += 32) {
        int cnt = min(32, s1 - base);
        int msrc = 0;
        float mw = 0.f;
        if (lane31 < cnt) { msrc = srcv[base + lane31]; mw = dinv[msrc] * dd; }
        int rounds = (cnt + 1) >> 1;
        int rp = ((rounds + 5) / 6) * 6;          // pad to full 6-batches
        for (int p = 0; p < rp; p += 6) {
            uint4 u[6];
            float w[6];
#pragma unroll
            for (int k = 0; k < 6; ++k) {
                int idx = (p + k) * 2 + qh;
                int sl = half * 32 + min(idx, 31);
                int src = __shfl(msrc, sl);
                float wk = __shfl(mw, sl);        // 0 beyond cnt (preload zeroed)
                if (idx > 31) wk = 0.f;           // clamped lanes: force dead weight
                w[k] = wk;
                u[k] = Xbf4[(size_t)src * 16 + l16];
            }
#pragma unroll
            for (int k = 0; k < 6; ++k) {
                acc[0] += w[k] * __uint_as_float(u[k].x << 16);
                acc[1] += w[k] * __uint_as_float(u[k].x & 0xFFFF0000u);
                acc[2] += w[k] * __uint_as_float(u[k].y << 16);
                acc[3] += w[k] * __uint_as_float(u[k].y & 0xFFFF0000u);
                acc[4] += w[k] * __uint_as_float(u[k].z << 16);
                acc[5] += w[k] * __uint_as_float(u[k].z & 0xFFFF0000u);
                acc[6] += w[k] * __uint_as_float(u[k].w << 16);
                acc[7] += w[k] * __uint_as_float(u[k].w & 0xFFFF0000u);
            }
        }
    }
#pragma unroll
    for (int j = 0; j < 8; ++j) acc[j] += __shfl_xor(acc[j], 16);   // combine the 2 quarters
    if ((lane & 16) == 0 && valid) {
        uint4 pk;
        pk.x = (unsigned)f2bf(acc[0]) | ((unsigned)f2bf(acc[1]) << 16);
        pk.y = (unsigned)f2bf(acc[2]) | ((unsigned)f2bf(acc[3]) << 16);
        pk.z = (unsigned)f2bf(acc[4]) | ((unsigned)f2bf(acc[5]) << 16);
        pk.w = (unsigned)f2bf(acc[6]) | ((unsigned)f2bf(acc[7]) << 16);
        ((uint4*)Abf)[(size_t)node * 16 + l16] = pk;
    }
}

// pass 1: MFMA product + BN column stats. NO LDS W-staging: B fragments read
// directly from the frag-major global Wt (32KB, L2-resident; per (nt,ks) the
// wave reads one coalesced 1KB line). Removes the 32KB LDS buffer (occupancy
// 4->8 blocks/CU) and the staging barrier's full-vmcnt drain.
__global__ __launch_bounds__(256) void gemm_stats_kernel(const unsigned short* __restrict__ Abf,
                                                         const unsigned short* __restrict__ Wf,
                                                         const float* __restrict__ bias,
                                                         float* __restrict__ gsum,
                                                         float* __restrict__ gsq) {
    __shared__ float ssum[HH], ssq[HH];
    int tid = threadIdx.x;
    if (tid < HH) { ssum[tid] = 0.f; ssq[tid] = 0.f; }
    __syncthreads();               // ssum/ssq init visible before end-of-kernel atomics

    int lane = tid & 63;
    int wave = tid >> 6;
    int mcol = lane & 15;
    int quad = lane >> 4;
    int rowbase = blockIdx.x * 128 + wave * 32;
    int row0 = rowbase + mcol;
    int row1 = row0 + 16;

    f32x4 acc[2][8];
#pragma unroll
    for (int mt = 0; mt < 2; ++mt)
#pragma unroll
        for (int nt = 0; nt < 8; ++nt) acc[mt][nt] = (f32x4){0.f, 0.f, 0.f, 0.f};

    s16x8 zf = {0, 0, 0, 0, 0, 0, 0, 0};
#pragma unroll
    for (int ks = 0; ks < 4; ++ks) {
        int k0 = ks * 32 + quad * 8;
        s16x8 a0 = (row0 < NN) ? *(const s16x8*)(Abf + (size_t)row0 * HH + k0) : zf;
        s16x8 a1 = (row1 < NN) ? *(const s16x8*)(Abf + (size_t)row1 * HH + k0) : zf;
#pragma unroll
        for (int nt = 0; nt < 8; ++nt) {
            s16x8 b = *(const s16x8*)(Wf + (((nt * 16 + ks * 4 + quad) * 16 + mcol) << 3));
            acc[0][nt] = __builtin_amdgcn_mfma_f32_16x16x32_bf16(a0, b, acc[0][nt], 0, 0, 0);
            acc[1][nt] = __builtin_amdgcn_mfma_f32_16x16x32_bf16(a1, b, acc[1][nt], 0, 0, 0);
        }
    }

    float s[8], sq[8];
#pragma unroll
    for (int nt = 0; nt < 8; ++nt) { s[nt] = 0.f; sq[nt] = 0.f; }
#pragma unroll
    for (int mt = 0; mt < 2; ++mt) {
        int rbase = rowbase + mt * 16 + quad * 4;
#pragma unroll
        for (int nt = 0; nt < 8; ++nt) {
            float bv = bias[nt * 16 + mcol];
            f32x4 a = acc[mt][nt];
#pragma unroll
            for (int reg = 0; reg < 4; ++reg) {
                if (rbase + reg < NN) {
                    float h = a[reg] + bv;
                    s[nt] += h; sq[nt] += h * h;
                }
            }
        }
    }
#pragma unroll
    for (int nt = 0; nt < 8; ++nt) {
        float v = s[nt];  v += __shfl_xor(v, 16);  v += __shfl_xor(v, 32);
        float w = sq[nt]; w += __shfl_xor(w, 16);  w += __shfl_xor(w, 32);
        if (quad == 0) {
            atomicAdd(&ssum[nt * 16 + mcol], v);
            atomicAdd(&ssq[nt * 16 + mcol], w);
        }
    }
    __syncthreads();
    if (tid < HH) {
        atomicAdd(&gsum[tid], ssum[tid]);
        atomicAdd(&gsq[tid], ssq[tid]);
    }
}

// pass 2: recompute MFMA product (proven cheaper than H-materialization, R5/R7),
// apply bias+BN+ReLU, store bf16 X. Same no-LDS B-read as stats.
__global__ __launch_bounds__(256) void gemm_apply_kernel(const unsigned short* __restrict__ Abf,
                                                         const unsigned short* __restrict__ Wf,
                                                         const float* __restrict__ bias,
                                                         const float* __restrict__ gsum,
                                                         const float* __restrict__ gsq,
                                                         const float* __restrict__ g,
                                                         const float* __restrict__ beta,
                                                         unsigned short* __restrict__ Xb16) {
    __shared__ float asc[HH], bsh[HH];
    int tid = threadIdx.x;
    if (tid < HH) {
        float mu = gsum[tid] * (1.f / (float)NN);
        float var = fmaxf(gsq[tid] * (1.f / (float)NN) - mu * mu, 0.f);
        float a = g[tid] * rsqrtf(var + 1e-5f);
        asc[tid] = a;
        bsh[tid] = a * (bias[tid] - mu) + beta[tid];   // o = a*acc + bsh (acc pre-bias)
    }
    __syncthreads();

    int lane = tid & 63;
    int wave = tid >> 6;
    int mcol = lane & 15;
    int quad = lane >> 4;
    int rowbase = blockIdx.x * 128 + wave * 32;
    int row0 = rowbase + mcol;
    int row1 = row0 + 16;

    f32x4 acc[2][8];
#pragma unroll
    for (int mt = 0; mt < 2; ++mt)
#pragma unroll
        for (int nt = 0; nt < 8; ++nt) acc[mt][nt] = (f32x4){0.f, 0.f, 0.f, 0.f};

    s16x8 zf = {0, 0, 0, 0, 0, 0, 0, 0};
#pragma unroll
    for (int ks = 0; ks < 4; ++ks) {
        int k0 = ks * 32 + quad * 8;
        s16x8 a0 = (row0 < NN) ? *(const s16x8*)(Abf + (size_t)row0 * HH + k0) : zf;
        s16x8 a1 = (row1 < NN) ? *(const s16x8*)(Abf + (size_t)row1 * HH + k0) : zf;
#pragma unroll
        for (int nt = 0; nt < 8; ++nt) {
            s16x8 b = *(const s16x8*)(Wf + (((nt * 16 + ks * 4 + quad) * 16 + mcol) << 3));
            acc[0][nt] = __builtin_amdgcn_mfma_f32_16x16x32_bf16(a0, b, acc[0][nt], 0, 0, 0);
            acc[1][nt] = __builtin_amdgcn_mfma_f32_16x16x32_bf16(a1, b, acc[1][nt], 0, 0, 0);
        }
    }

#pragma unroll
    for (int mt = 0; mt < 2; ++mt) {
        int rbase = rowbase + mt * 16 + quad * 4;
#pragma unroll
        for (int nt = 0; nt < 8; ++nt) {
            int col = nt * 16 + mcol;
            float av = asc[col], bv = bsh[col];
            f32x4 a = acc[mt][nt];
#pragma unroll
            for (int reg = 0; reg < 4; ++reg) {
                int r = rbase + reg;
                if (r < NN) {
                    float o = fmaxf(av * a[reg] + bv, 0.f);
                    Xb16[(size_t)r * HH + col] = f2bf(o);
                }
            }
        }
    }
}

// ---------------- pooling + fc ----------------

__global__ void pool_kernel(const unsigned* __restrict__ Xbf, const int* __restrict__ gstart,
                            const int* __restrict__ gend, float* __restrict__ poolsum) {
    int g = blockIdx.x;
    int sp = blockIdx.y;
    int t = threadIdx.x;           // 64: each handles 2 cols
    int s = gstart[g], e = gend[g];
    if (e <= s) return;
    int len = e - s;
    int chunk = (len + PSPLIT - 1) / PSPLIT;
    int cs = s + sp * chunk;
    int ce = min(cs + chunk, e);
    if (cs >= ce) return;
    float2 acc = make_float2(0.f, 0.f);
    for (int i = cs; i < ce; ++i) {
        unsigned u = Xbf[(size_t)i * 64 + t];
        acc.x += __uint_as_float(u << 16);
        acc.y += __uint_as_float(u & 0xFFFF0000u);
    }
    atomicAdd(&poolsum[g * HH + 2 * t], acc.x);
    atomicAdd(&poolsum[g * HH + 2 * t + 1], acc.y);
}

__global__ void fc_kernel(const float* __restrict__ poolsum, const int* __restrict__ gstart,
                          const int* __restrict__ gend, const float* __restrict__ fc_w,
                          const float* __restrict__ fc_b, float* __restrict__ out) {
    int g = blockIdx.x;
    int o = threadIdx.x;
    int cnt = gend[g] - gstart[g];
    float inv = (cnt > 0) ? (1.f / (float)cnt) : 0.f;
    float acc = fc_b[o];
    for (int k = 0; k < HH; ++k) acc += (poolsum[g * HH + k] * inv) * fc_w[k * HH + o];
    out[g * HH + o] = acc;
}

// ---------------- launch ----------------

extern "C" void kernel_launch(void* const* d_in, const int* in_sizes, int n_in,
                              void* d_out, int out_size, void* d_ws, size_t ws_size,
                              hipStream_t stream) {
    const float* x     = (const float*)d_in[0];
    const int*   ei    = (const int*)d_in[1];
    const int*   batch = (const int*)d_in[2];
    const float* Wl[3]    = {(const float*)d_in[3], (const float*)d_in[7], (const float*)d_in[11]};
    const float* bl[3]    = {(const float*)d_in[4], (const float*)d_in[8], (const float*)d_in[12]};
    const float* gl[3]    = {(const float*)d_in[5], (const float*)d_in[9], (const float*)d_in[13]};
    const float* betal[3] = {(const float*)d_in[6], (const float*)d_in[10], (const float*)d_in[14]};
    const float* fc_w = (const float*)d_in[15];
    const float* fc_b = (const float*)d_in[16];
    float* out = (float*)d_out;

    char* ws = (char*)d_ws;
    size_t off = 0;
    auto take = [&](size_t n) -> void* {
        void* p = ws + off;
        off = (off + n + 255) & ~(size_t)255;
        return p;
    };
    int*   bucketSlotStart = (int*)take((size_t)NB * 4);
    int*   cursor          = (int*)take((size_t)NB * 4);
    unsigned* ebuf         = (unsigned*)take((size_t)NB * BCAP * 4);
    int*   col_start       = (int*)take((size_t)(NN + 1) * 4);
    float* dinv            = (float*)take((size_t)NN * 4);
    int*   srcv            = (int*)take((size_t)TOT * 4);
    float* gsum            = (float*)take(HH * 4);
    float* gsq             = (float*)take(HH * 4);
    int*   gstart          = (int*)take(GG * 4);
    int*   gend            = (int*)take(GG * 4);
    float* poolsum         = (float*)take((size_t)GG * HH * 4);
    unsigned short* wt     = (unsigned short*)take((size_t)3 * HH * HH * 2);
    unsigned* Xbf          = (unsigned*)take((size_t)NN * 64 * 4);
    unsigned short* Abf    = (unsigned short*)take((size_t)NN * HH * 2);

    setup_kernel<<<(NN * 64 + 255) / 256, 256, 0, stream>>>(x, batch, Wl[0], Wl[1], Wl[2],
                                                            Xbf, cursor, gstart, gend, poolsum, wt);
    bfill2_kernel<<<(EE + FCHUNK - 1) / FCHUNK, 256, 0, stream>>>(ei, cursor, ebuf);
    bscan_kernel<<<1, 1024, 0, stream>>>(cursor, bucketSlotStart, col_start);
    bproc_kernel<<<NB, 256, 0, stream>>>(ebuf, cursor, bucketSlotStart, col_start, dinv, srcv);

    const int aggBlocks = (((NN + 1) / 2) * 64 + 255) / 256;   // 2 nodes per wave
    for (int l = 0; l < 3; ++l) {
        const unsigned short* W = wt + (size_t)l * HH * HH;
        agg_kernel<<<aggBlocks, 256, 0, stream>>>((const uint4*)Xbf, col_start, srcv,
                                                  dinv, Abf, gsum, gsq);
        gemm_stats_kernel<<<(NN + 127) / 128, 256, 0, stream>>>(Abf, W, bl[l], gsum, gsq);
        gemm_apply_kernel<<<(NN + 127) / 128, 256, 0, stream>>>(Abf, W, bl[l], gsum, gsq,
                                                                gl[l], betal[l],
                                                                (unsigned short*)Xbf);
    }

    pool_kernel<<<dim3(GG, PSPLIT), 64, 0, stream>>>(Xbf, gstart, gend, poolsum);
    fc_kernel<<<GG, 128, 0, stream>>>(poolsum, gstart, gend, fc_w, fc_b, out);
}